// Round 9
// baseline (443.057 us; speedup 1.0000x reference)
//
#include <hip/hip_runtime.h>
#include <math.h>

// Problem constants
static constexpr int H = 256, L = 141, N1 = 9, N2 = 34, N3 = 98;
static constexpr int B = 64, S = 512;

typedef __attribute__((ext_vector_type(8))) _Float16 f16x8;
typedef __attribute__((ext_vector_type(4))) float f32x4;

__device__ inline unsigned short f2h(float x) {
    _Float16 h = (_Float16)x;
    return __builtin_bit_cast(unsigned short, h);
}
__device__ inline float sigf(float x) { return 1.f / (1.f + __expf(-x)); }

__device__ inline void gload_lds16(const void* g, void* l) {
    __builtin_amdgcn_global_load_lds(
        (const __attribute__((address_space(1))) void*)g,
        (__attribute__((address_space(3))) void*)l, 16, 0, 0);
}

// ---------------------------------------------------------------------------
// prep: fuses conv_ttW (24 blocks) + transp_t64 for out_W (564*3 blocks).
// ---------------------------------------------------------------------------
__global__ __launch_bounds__(256) void prep(
    const float* __restrict__ ttW, unsigned short* __restrict__ Bt,
    const float* __restrict__ outW, unsigned short* __restrict__ outWh)
{
    __shared__ unsigned short Tl[32][257];
    __shared__ unsigned short T2[64 * 65];
    const int tid = threadIdx.x;
    if (blockIdx.x < 24) {
        const int t = blockIdx.x;
        #pragma unroll
        for (int p = 0; p < 32; p++) {
            int lin = p * 256 + tid;
            int r = lin >> 8, c = lin & 255;
            Tl[r][c] = f2h(ttW[(long)(t * 32 + r) * 256 + c]);
        }
        __syncthreads();
        unsigned short v[32];
        #pragma unroll
        for (int kin = 0; kin < 32; kin++) v[kin] = Tl[kin][tid];
        uint4* dst = (uint4*)(Bt + ((long)t * 256 + tid) * 32);
        #pragma unroll
        for (int q = 0; q < 4; q++) dst[q] = ((const uint4*)v)[q];
    } else {
        const int u = blockIdx.x - 24;
        const int r0 = (u % 564) * 64, c0 = (u / 564) * 64;
        const int R = 36096, C = 141;
        #pragma unroll
        for (int p = 0; p < 16; p++) {
            int lin = p * 256 + tid;
            int r = lin >> 6, c = lin & 63;
            int gc = c0 + c;
            float v = (gc < C) ? outW[(long)(r0 + r) * C + gc] : 0.f;
            T2[c * 65 + r] = f2h(v);
        }
        __syncthreads();
        #pragma unroll
        for (int p = 0; p < 16; p++) {
            int lin = p * 256 + tid;
            int c = lin >> 6, r = lin & 63;
            if (c0 + c < C)
                outWh[(long)(c0 + c) * R + r0 + r] = T2[c * 65 + r];
        }
    }
}

// ---------------------------------------------------------------------------
// text_gemm4: 128-row m-tile version of the proven text_gemm3 pipeline.
// Grid 256 blocks x 1024 thr (16 waves). Wave = 32m x 64n, acc[2][4],
// 8 MFMA/iter — per-wave work IDENTICAL to text_gemm3; iterations (and
// barrier-stall) per output row HALVED. Per-SIMD occupancy unchanged
// (256x16 waves = 4/SIMD, same as 512x8 at 2 blk/CU).
//  - A: 1 float4/thread/step (128 rows x 32 fp32), issued 2 steps early,
//    cvt f16 -> swizzled ds_write (chunk8 ^= (row&3)<<1), dbuf LDS.
//  - B: 1 gload_lds/thread/step (wave stages 16 rows), triple-buffered,
//    source pre-swizzle chunk16 ^= ((row>>1)&3)  [= (l&3)^((l>>3)&3)].
//  - Counted vmcnt: prologue 3/2, body 2/2 (queue invariant
//    [A(t+2), B(t+2)] across each barrier). K-order per output element
//    unchanged -> bit-identical to text_gemm3.
//  - Epilogue: two-half transpose via T[256][72] (36 KB LDS alias).
// ---------------------------------------------------------------------------
__global__ __launch_bounds__(1024, 1) void text_gemm4(
    const float* __restrict__ Af,            // [32768][768] fp32
    const unsigned short* __restrict__ Bt,   // [24][256][32] f16 tiled
    const float* __restrict__ bias,          // [256]
    unsigned short* __restrict__ outH,       // [32768][256] fp16
    unsigned short* __restrict__ outHT)      // [64][256][512] fp16
{
    __shared__ unsigned short smem[32768];   // 64 KB
    unsigned short* As = smem;               // 2 x [128][32] (8192 shorts)
    unsigned short* Bs = smem + 8192;        // 3 x [256][32] (24576 shorts)
    unsigned short* T  = smem;               // epilogue alias: [256][72]

    const int tid  = threadIdx.x;
    const int wave = tid >> 6, lane = tid & 63;
    const int quad = lane >> 4, l16 = lane & 15;
    const int m0 = blockIdx.x * 128;
    const int wm = (wave >> 2) * 32;         // 4 m-groups
    const int wn = (wave & 3) * 64;          // 4 n-groups

    // ---- A staging: 1 float4/thread/step covers 128 rows x 32 fp32 ----
    const int arow = tid >> 3;               // 0..127
    const int ac16 = tid & 7;
    const float* aSrc = Af + (long)(m0 + arow) * 768 + ac16 * 4;
    const int ac8d = ac16 ^ ((arow & 3) << 1);
    const int aWoff = arow * 32 + ac8d * 4;  // shorts

    // ---- B staging: wave stages rows wave*16..+15 (1 gload/thread) ----
    const int bsc = (lane & 3) ^ ((lane >> 3) & 3);
    const long bSrcOff = (long)(wave * 16 + (lane >> 2)) * 32 + bsc * 8;
    const int bDst = (wave * 16) * 32;       // shorts

    int aro[2], bro[4];
    #pragma unroll
    for (int i = 0; i < 2; i++) {
        int r = wm + i * 16 + l16;
        aro[i] = r * 32 + ((quad * 2) ^ ((r & 3) << 1)) * 4;
    }
    #pragma unroll
    for (int j = 0; j < 4; j++) {
        int n = wn + j * 16 + l16;
        bro[j] = n * 32 + ((quad ^ ((n >> 1) & 3)) << 3);
    }

    f32x4 acc[2][4] = {};
    float4 ar0, ar1;

    auto issueB = [&](int kt, int pb) {
        gload_lds16(Bt + (long)kt * 8192 + bSrcOff, Bs + pb * 8192 + bDst);
    };
    auto writeA = [&](const float4& v, int pa) {
        unsigned int p0 = f2h(v.x) | ((unsigned int)f2h(v.y) << 16);
        unsigned int p1 = f2h(v.z) | ((unsigned int)f2h(v.w) << 16);
        *(uint2*)&As[pa * 4096 + aWoff] = make_uint2(p0, p1);
    };

    // ---- prologue: queue [A0, B0, A1, B1] ----
    ar0 = *(const float4*)(aSrc + 0 * 32);
    issueB(0, 0);
    ar1 = *(const float4*)(aSrc + 1 * 32);
    issueB(1, 1);
    asm volatile("s_waitcnt vmcnt(3)" ::: "memory");   // A(0) landed
    writeA(ar0, 0);
    asm volatile("s_waitcnt vmcnt(2)" ::: "memory");   // B(0) landed (own)
    asm volatile("s_waitcnt lgkmcnt(0)" ::: "memory");
    asm volatile("s_barrier" ::: "memory");

    // body entry invariant: As[pa]=tile t, Bs[pr]=tile t,
    // vm queue = [A(t+1):1, B(t+1):1].
    auto body = [&](int t, float4& arIn, float4& arOut, int pa, int pr) {
        int kt2 = (t + 2 <= 23) ? t + 2 : 23;
        arOut = *(const float4*)(aSrc + kt2 * 32);      // queue: +A(t+2)
        f16x8 a[2], b[4];
        const unsigned short* ab = As + pa * 4096;
        const unsigned short* bb = Bs + pr * 8192;
        #pragma unroll
        for (int i = 0; i < 2; i++) a[i] = *(const f16x8*)&ab[aro[i]];
        #pragma unroll
        for (int j = 0; j < 4; j++) b[j] = *(const f16x8*)&bb[bro[j]];
        #pragma unroll
        for (int i = 0; i < 2; i++)
            #pragma unroll
            for (int j = 0; j < 4; j++)
                acc[i][j] = __builtin_amdgcn_mfma_f32_16x16x32_f16(
                    a[i], b[j], acc[i][j], 0, 0, 0);
        asm volatile("s_waitcnt vmcnt(2)" ::: "memory"); // retire A(t+1)
        writeA(arIn, pa ^ 1);
        int pw = pr + 2; if (pw >= 3) pw -= 3;
        issueB(kt2, pw);                                 // queue: +B(t+2)
        asm volatile("s_waitcnt vmcnt(2)" ::: "memory"); // retire B(t+1)
        asm volatile("s_waitcnt lgkmcnt(0)" ::: "memory");
        asm volatile("s_barrier" ::: "memory");
    };

    int pr = 0;
    #pragma unroll 1
    for (int t = 0; t < 24; t += 2) {
        body(t,     ar1, ar0, 0, pr);
        int pr1 = pr + 1; if (pr1 >= 3) pr1 -= 3;
        body(t + 1, ar0, ar1, 1, pr1);
        pr = pr1 + 1; if (pr >= 3) pr -= 3;
    }
    asm volatile("s_waitcnt vmcnt(0)" ::: "memory");
    __syncthreads();

    // ---- epilogue: tanh + bias; outH direct; outHT via 2-half transpose ----
    float bv[4];
    #pragma unroll
    for (int j = 0; j < 4; j++) bv[j] = bias[wn + j * 16 + l16];
    const int bb2 = m0 >> 9, s0base = m0 & 511;
    const int myhalf = wave >> 3;            // 0: m-local<64, 1: >=64

    #pragma unroll
    for (int h = 0; h < 2; h++) {
        __syncthreads();
        if (myhalf == h) {
            #pragma unroll
            for (int i = 0; i < 2; i++) {
                #pragma unroll
                for (int j = 0; j < 4; j++) {
                    const int mlb = wm + i * 16 + quad * 4;   // 0..124
                    const int n   = wn + j * 16 + l16;
                    unsigned short hv[4];
                    #pragma unroll
                    for (int r = 0; r < 4; r++) {
                        float v = tanhf(acc[i][j][r] + bv[j]);
                        hv[r] = f2h(v);
                        outH[(long)(m0 + mlb + r) * 256 + n] = hv[r];
                    }
                    uint2 p;
                    p.x = hv[0] | ((unsigned int)hv[1] << 16);
                    p.y = hv[2] | ((unsigned int)hv[3] << 16);
                    *(uint2*)&T[n * 72 + (mlb - h * 64)] = p;
                }
            }
        }
        __syncthreads();
        {
            const int n = tid >> 2, q = tid & 3;     // 256 rows x 4 thr
            const uint4* src = (const uint4*)&T[n * 72 + q * 16];
            uint4* dst = (uint4*)&outHT[((long)bb2 * 256 + n) * 512
                                        + s0base + h * 64 + q * 16];
            dst[0] = src[0]; dst[1] = src[1];
        }
    }
}

// ---------------------------------------------------------------------------
// gates_pre: fuses gate_pre (28x141 units) + pre2 (4x273 units). Unchanged.
// ---------------------------------------------------------------------------
__global__ __launch_bounds__(256) void gates_pre(
    const float* __restrict__ le,
    const float* W0, const float* W1, const float* W2, const float* W3,
    const float* W4, const float* W5, const float* W6,
    const float* b0, const float* b1, const float* b2, const float* b3,
    const float* b4, const float* b5, const float* b6,
    const float* __restrict__ Amat, const float* __restrict__ w23,
    const float* __restrict__ w12, const float* __restrict__ Wp,
    const float* __restrict__ wf2_W,
    float* __restrict__ G, float* __restrict__ tmpP,
    float* __restrict__ wv2f, float* __restrict__ wv1f)
{
    __shared__ float smem[768];
    const int tid = threadIdx.x;
    const int nl = tid & 63, ks = tid >> 6;
    if (blockIdx.x < 28 * 141) {
        const int u = blockIdx.x;
        const int bx = u % 28, m = u / 28;
        const int j = bx >> 2, x = bx & 3, n = x * 64 + nl;
        float* ls = smem; float* red = smem + 256;
        ls[tid] = le[(long)m * 256 + tid];
        __syncthreads();
        const float *W, *bb;
        switch (j) {
            case 0: W = W0; bb = b0; break;  case 1: W = W1; bb = b1; break;
            case 2: W = W2; bb = b2; break;  case 3: W = W3; bb = b3; break;
            case 4: W = W4; bb = b4; break;  case 5: W = W5; bb = b5; break;
            default: W = W6; bb = b6;
        }
        float a0 = 0, a1 = 0, a2 = 0, a3 = 0;
        for (int k = ks; k + 12 < 256; k += 16) {
            long o = (long)k * 256 + n;
            a0 += ls[k] * W[o];        a1 += ls[k + 4] * W[o + 1024];
            a2 += ls[k + 8] * W[o + 2048]; a3 += ls[k + 12] * W[o + 3072];
        }
        red[tid] = a0 + a1 + a2 + a3;
        __syncthreads();
        if (ks == 0)
            G[((long)j * 141 + m) * 256 + n] =
                red[nl] + red[64 + nl] + red[128 + nl] + red[192 + nl] + bb[n];
    } else {
        const int u = blockIdx.x - 28 * 141;
        const int x = u % 4, y = u / 4, n = x * 64 + nl;
        int job, m, K1;
        if (y < 141)      { job = 0; m = y;       K1 = 141; }
        else if (y < 239) { job = 1; m = y - 141; K1 = 34; }
        else              { job = 2; m = y - 239; K1 = 9; }
        float* cs = smem; float* t = smem + 256; float* red = smem + 512;
        if (tid < K1)
            cs[tid] = (job == 0) ? Amat[(long)m * 141 + tid]
                    : (job == 1) ? w23[(long)tid * 98 + m]
                                 : w12[(long)tid * 34 + m];
        __syncthreads();
        const float* s1 = (job == 1) ? le + 9 * 256 : le;
        float acc = 0;
        #pragma unroll 4
        for (int k = 0; k < K1; k++) acc += cs[k] * s1[(long)k * 256 + tid];
        t[tid] = acc;
        __syncthreads();
        const float* W = (job == 0) ? Wp : wf2_W;
        float a0 = 0, a1 = 0, a2 = 0, a3 = 0;
        for (int k = ks; k + 12 < 256; k += 16) {
            long o = (long)k * 256 + n;
            a0 += t[k] * W[o];        a1 += t[k + 4] * W[o + 1024];
            a2 += t[k + 8] * W[o + 2048]; a3 += t[k + 12] * W[o + 3072];
        }
        red[tid] = a0 + a1 + a2 + a3;
        __syncthreads();
        if (ks == 0) {
            float tot = red[nl] + red[64 + nl] + red[128 + nl] + red[192 + nl];
            if (job == 0)      tmpP[(long)m * 256 + n] = fmaxf(tot, 0.f);
            else if (job == 1) wv2f[(long)m * 256 + n] = tot;
            else               wv1f[(long)m * 256 + n] = tot;
        }
    }
}

// L1: elementwise gates -> h11,c11 (9r) and h32,c32 (98r). grid(107)
__global__ __launch_bounds__(256) void ew1(
    const float* __restrict__ G, float* __restrict__ h11, float* __restrict__ c11,
    float* __restrict__ h32, float* __restrict__ c32)
{
    int y = blockIdx.x, n = threadIdx.x;
    if (y < 9) {
        int m = y;
        float iv = sigf(G[(0L * 141 + m) * 256 + n]);
        float ov = sigf(G[(2L * 141 + m) * 256 + n]);
        float uv = tanhf(G[(3L * 141 + m) * 256 + n]);
        float cv = iv * uv;
        c11[m * 256 + n] = cv; h11[m * 256 + n] = ov * tanhf(cv);
    } else {
        int r = y - 9, grow = 43 + r;
        float iv = sigf(G[(4L * 141 + grow) * 256 + n]);
        float ov = sigf(G[(5L * 141 + grow) * 256 + n]);
        float uv = tanhf(G[(6L * 141 + grow) * 256 + n]);
        float cv = iv * uv;
        c32[r * 256 + n] = cv; h32[r * 256 + n] = ov * tanhf(cv);
    }
}

// chain_mm: fused sparse/row matmuls.
__global__ __launch_bounds__(256) void chain_mm(int phase,
    const float* __restrict__ w12, const float* __restrict__ w23,
    const float* __restrict__ fre23, const float* __restrict__ fre12,
    const float* __restrict__ h11, const float* __restrict__ c11,
    const float* __restrict__ h32,
    const float* __restrict__ h21, const float* __restrict__ c21,
    const float* __restrict__ h22,
    const float* __restrict__ wv2f, const float* __restrict__ wv1f,
    const float* __restrict__ wf2_b, const float* __restrict__ uf2_W,
    const float* __restrict__ c32, const float* __restrict__ c22,
    float* __restrict__ h21t, float* __restrict__ c21p,
    float* __restrict__ h22t, float* __restrict__ fcb,
    float* __restrict__ h31t, float* __restrict__ c31p,
    float* __restrict__ h12t, float* __restrict__ fc2b)
{
    __shared__ float cs[256];
    __shared__ float red[256];
    const int x = blockIdx.x, y = blockIdx.y;
    const int tid = threadIdx.x, nl = tid & 63, ks = tid >> 6, n = x * 64 + nl;
    int job, m;
    if (phase == 0) {
        if (y < 34)       { job = 0; m = y; }
        else if (y < 68)  { job = 1; m = y - 34; }
        else if (y < 102) { job = 2; m = y - 68; }
        else              { job = 3; m = y - 102; }
    } else {
        if (y < 98)       { job = 0; m = y; }
        else if (y < 196) { job = 1; m = y - 98; }
        else if (y < 205) { job = 2; m = y - 196; }
        else              { job = 3; m = y - 205; }
    }
    if (job < 3) {
        int K; const float* src; float* dst;
        if (phase == 0) {
            K = (job == 2) ? 98 : 9;
            src = (job == 0) ? h11 : (job == 1) ? c11 : h32;
            dst = (job == 0) ? h21t : (job == 1) ? c21p : h22t;
            if (tid < K)
                cs[tid] = (job == 2) ? fre23[(long)m * 98 + tid]
                                     : w12[(long)tid * 34 + m];
        } else {
            K = 34;
            src = (job == 0) ? h21 : (job == 1) ? c21 : h22;
            dst = (job == 0) ? h31t : (job == 1) ? c31p : h12t;
            if (tid < K)
                cs[tid] = (job == 2) ? fre12[(long)m * 34 + tid]
                                     : w23[(long)tid * 98 + m];
        }
        __syncthreads();
        float a0 = 0;
        for (int k = ks; k < K; k += 4) a0 += cs[k] * src[(long)k * 256 + n];
        red[tid] = a0;
        __syncthreads();
        if (ks == 0)
            dst[(long)m * 256 + n] = red[nl] + red[64 + nl] + red[128 + nl] + red[192 + nl];
    } else {
        const float* row = (phase == 0) ? h32 + m * 256 : h22 + m * 256;
        const float* pre = (phase == 0) ? wv2f : wv1f;
        const float* cm  = (phase == 0) ? c32 : c22;
        float* dst       = (phase == 0) ? fcb : fc2b;
        cs[tid] = row[tid];
        __syncthreads();
        float a0 = 0, a1 = 0, a2 = 0, a3 = 0;
        for (int k = ks; k + 12 < 256; k += 16) {
            long o = (long)k * 256 + n;
            a0 += cs[k] * uf2_W[o];        a1 += cs[k + 4] * uf2_W[o + 1024];
            a2 += cs[k + 8] * uf2_W[o + 2048]; a3 += cs[k + 12] * uf2_W[o + 3072];
        }
        red[tid] = a0 + a1 + a2 + a3;
        __syncthreads();
        if (ks == 0) {
            float tot = red[nl] + red[64 + nl] + red[128 + nl] + red[192 + nl]
                      + pre[(long)m * 256 + n] + wf2_b[n];
            dst[(long)m * 256 + n] = sigf(tot) * cm[(long)m * 256 + n];
        }
    }
}

// lstm_fused: fused gate matmuls + elementwise.
__global__ __launch_bounds__(256) void lstm_fused(int phase,
    const float* __restrict__ G,
    const float* __restrict__ h21t, const float* __restrict__ c21p,
    const float* __restrict__ h22t, const float* __restrict__ fcb,
    const float* __restrict__ h31t, const float* __restrict__ c31p,
    const float* __restrict__ h12t, const float* __restrict__ fc2b,
    const float* __restrict__ w23, const float* __restrict__ w12,
    const float* __restrict__ ui1, const float* __restrict__ uf1,
    const float* __restrict__ uo1, const float* __restrict__ uu1,
    const float* __restrict__ ui2, const float* __restrict__ uo2,
    const float* __restrict__ uu2,
    float* __restrict__ h21, float* __restrict__ c21,
    float* __restrict__ h22, float* __restrict__ c22,
    float* __restrict__ h31, float* __restrict__ h12)
{
    __shared__ float hs[256];
    __shared__ float cs[128];
    __shared__ float red[1024];
    const int x = blockIdx.x, y = blockIdx.y;
    const int tid = threadIdx.x, nl = tid & 63, ks = tid >> 6, n = x * 64 + nl;
    bool modef; int m, grow, Kx = 0;
    const float *hrow, *U0, *U1, *U2, *U3 = nullptr, *Sx = nullptr, *cmod = nullptr;
    float *ho, *co = nullptr;
    if (phase == 0) {
        if (y < 34) { modef = true;  m = y;      grow = 9 + m;  hrow = h21t;
                      U0 = ui1; U1 = uf1; U2 = uo1; U3 = uu1; cmod = c21p; ho = h21; co = c21; }
        else        { modef = false; m = y - 34; grow = 9 + m;  hrow = h22t;
                      U0 = ui2; U1 = uo2; U2 = uu2; Sx = fcb; Kx = 98; ho = h22; co = c22;
                      if (tid < 98) cs[tid] = w23[(long)m * 98 + tid]; }
    } else {
        if (y < 98) { modef = true;  m = y;      grow = 43 + m; hrow = h31t;
                      U0 = ui1; U1 = uf1; U2 = uo1; U3 = uu1; cmod = c31p; ho = h31; co = nullptr; }
        else        { modef = false; m = y - 98; grow = m;      hrow = h12t;
                      U0 = ui2; U1 = uo2; U2 = uu2; Sx = fc2b; Kx = 34; ho = h12; co = nullptr;
                      if (tid < 34) cs[tid] = w12[(long)m * 34 + tid]; }
    }
    hs[tid] = hrow[(long)m * 256 + tid];
    __syncthreads();
    float a0 = 0, a1 = 0, a2 = 0, a3 = 0;
    if (modef) {
        for (int k = ks; k < 256; k += 4) {
            float xv = hs[k]; long o = (long)k * 256 + n;
            a0 += xv * U0[o]; a1 += xv * U1[o]; a2 += xv * U2[o]; a3 += xv * U3[o];
        }
    } else {
        for (int k = ks; k < 256; k += 4) {
            float xv = hs[k]; long o = (long)k * 256 + n;
            a0 += xv * U0[o]; a1 += xv * U1[o]; a2 += xv * U2[o];
        }
        for (int k = ks; k < Kx; k += 4) a3 += cs[k] * Sx[(long)k * 256 + n];
    }
    red[tid] = a0; red[256 + tid] = a1; red[512 + tid] = a2; red[768 + tid] = a3;
    __syncthreads();
    if (ks == 0) {
        float t0 = 0, t1 = 0, t2 = 0, t3 = 0;
        #pragma unroll
        for (int s2 = 0; s2 < 4; s2++) {
            t0 += red[s2 * 64 + nl];       t1 += red[256 + s2 * 64 + nl];
            t2 += red[512 + s2 * 64 + nl]; t3 += red[768 + s2 * 64 + nl];
        }
        if (modef) {
            float ti = t0 + G[(0L * 141 + grow) * 256 + n];
            float tf = t1 + G[(1L * 141 + grow) * 256 + n];
            float to = t2 + G[(2L * 141 + grow) * 256 + n];
            float tu = t3 + G[(3L * 141 + grow) * 256 + n];
            float cv = sigf(ti) * tanhf(tu) + sigf(tf) * cmod[(long)m * 256 + n];
            ho[(long)m * 256 + n] = sigf(to) * tanhf(cv);
            if (co) co[(long)m * 256 + n] = cv;
        } else {
            float ti = t0 + G[(4L * 141 + grow) * 256 + n];
            float to = t1 + G[(5L * 141 + grow) * 256 + n];
            float tu = t2 + G[(6L * 141 + grow) * 256 + n];
            float cv = sigf(ti) * tanhf(tu) + t3;
            ho[(long)m * 256 + n] = sigf(to) * tanhf(cv);
            if (co) co[(long)m * 256 + n] = cv;
        }
    }
}

// le_h[l] = fp16( [h?1(l) | h?2(l) | tmpP(l)] @ mix_W + mix_b ). grid (4,141)
__global__ __launch_bounds__(256) void mix_mm(
    const float* __restrict__ h11, const float* __restrict__ h12,
    const float* __restrict__ h21, const float* __restrict__ h22,
    const float* __restrict__ h31, const float* __restrict__ h32,
    const float* __restrict__ tmpP, const float* __restrict__ mix_W,
    const float* __restrict__ mix_b, unsigned short* __restrict__ le_h)
{
    __shared__ float ls[768];
    __shared__ float red[256];
    const int x = blockIdx.x, l = blockIdx.y;
    const int tid = threadIdx.x, nl = tid & 63, ks = tid >> 6, n = x * 64 + nl;
    const float *pa, *pb; int r;
    if (l < 9)       { pa = h11; pb = h12; r = l; }
    else if (l < 43) { pa = h21; pb = h22; r = l - 9; }
    else             { pa = h31; pb = h32; r = l - 43; }
    for (int j = tid; j < 768; j += 256) {
        float v;
        if (j < 256)      v = pa[r * 256 + j];
        else if (j < 512) v = pb[r * 256 + (j - 256)];
        else              v = tmpP[l * 256 + (j - 512)];
        ls[j] = v;
    }
    __syncthreads();
    float a0 = 0, a1 = 0, a2 = 0, a3 = 0;
    for (int k = ks; k + 12 < 768; k += 16) {
        long o = (long)k * 256 + n;
        a0 += ls[k] * mix_W[o];        a1 += ls[k + 4] * mix_W[o + 1024];
        a2 += ls[k + 8] * mix_W[o + 2048]; a3 += ls[k + 12] * mix_W[o + 3072];
    }
    red[tid] = a0 + a1 + a2 + a3;
    __syncthreads();
    if (ks == 0) {
        float tot = red[nl] + red[64 + nl] + red[128 + nl] + red[192 + nl] + mix_b[n];
        le_h[(long)l * 256 + n] = f2h(tot);
    }
}

// ---------------------------------------------------------------------------
// att_logits2: logits + pad-mask + ROW SOFTMAX fused (round-8, verified).
// ---------------------------------------------------------------------------
__global__ __launch_bounds__(512, 1) void att_logits2(
    const unsigned short* __restrict__ le_h,    // [141][256] f16
    const unsigned short* __restrict__ text_h,  // [64*512][256] f16
    const int* __restrict__ tokens,             // [64][512]
    unsigned short* __restrict__ att_h)         // [64*141][512] f16
{
    __shared__ unsigned short A_s[64 * 256];    // 32 KB
    __shared__ unsigned short Bs[2][512 * 32];  // 64 KB
    __shared__ float redm[8][32];
    __shared__ float reds[8][32];
    const int tid  = threadIdx.x;
    const int wave = tid >> 6, lane = tid & 63;
    const int quad = lane >> 4, l16 = lane & 15;
    const int m0 = blockIdx.x * 64;
    const int b  = blockIdx.y;
    const int wm = (wave >> 2) * 32;            // 2 m-groups
    const int wn = (wave & 3) * 128;            // 4 n-groups x 128 cols

    const int bsc = (lane & 3) ^ ((lane >> 3) & 3);
    const long bOffBase = (long)(b * 512 + wave * 64 + (lane >> 2)) * 256 + bsc * 8;
    const int bDstBase = (wave * 64) * 32;      // shorts
    auto issueB = [&](int kt, int pb) {
        #pragma unroll
        for (int q = 0; q < 4; q++)
            gload_lds16(text_h + bOffBase + (long)q * 16 * 256 + kt * 32,
                        &Bs[pb][bDstBase + q * 16 * 32]);
    };

    int abase[2], axm[2], bro[8];
    #pragma unroll
    for (int i = 0; i < 2; i++) {
        int r = wm + i * 16 + l16;
        abase[i] = r * 256; axm[i] = r & 7;
    }
    #pragma unroll
    for (int j = 0; j < 8; j++) {
        int n = wn + j * 16 + l16;
        bro[j] = n * 32 + ((quad ^ ((n >> 1) & 3)) << 3);
    }

    #pragma unroll
    for (int p = 0; p < 4; p++) {
        int row = p * 16 + (tid >> 5);
        int c   = tid & 31;
        int grow = m0 + row; if (grow > L - 1) grow = L - 1;
        gload_lds16(le_h + (long)grow * 256 + ((c ^ (row & 7)) << 3),
                    A_s + p * 4096 + wave * 512);
    }
    issueB(0, 0);
    issueB(1, 1);
    asm volatile("s_waitcnt vmcnt(4)" ::: "memory");   // A(4)+B0(4) landed
    asm volatile("s_barrier" ::: "memory");

    f32x4 acc[2][8] = {};
    #pragma unroll 1
    for (int t = 0; t < 8; t++) {
        const int pb = t & 1;
        f16x8 a[2], bf[8];
        #pragma unroll
        for (int i = 0; i < 2; i++)
            a[i] = *(const f16x8*)&A_s[abase[i] + (((t * 4 + quad) ^ axm[i]) << 3)];
        const unsigned short* bb = &Bs[pb][0];
        #pragma unroll
        for (int j = 0; j < 8; j++) bf[j] = *(const f16x8*)&bb[bro[j]];
        #pragma unroll
        for (int i = 0; i < 2; i++)
            #pragma unroll
            for (int j = 0; j < 8; j++)
                acc[i][j] = __builtin_amdgcn_mfma_f32_16x16x32_f16(
                    a[i], bf[j], acc[i][j], 0, 0, 0);
        if (t < 7) {
            asm volatile("s_waitcnt lgkmcnt(0)" ::: "memory");
            asm volatile("s_barrier" ::: "memory");
            int kt2 = (t + 2 <= 7) ? t + 2 : 7;
            issueB(kt2, pb);
            asm volatile("s_waitcnt vmcnt(4)" ::: "memory");
            asm volatile("s_barrier" ::: "memory");
        }
    }
    asm volatile("s_waitcnt vmcnt(0)" ::: "memory");

    float mvv[8];
    #pragma unroll
    for (int j = 0; j < 8; j++) {
        int gs = wn + j * 16 + l16;
        int tok = tokens[(long)b * 512 + gs];
        mvv[j] = (tok == 0 || tok == 101 || tok == 102) ? 1e30f : 0.f;
    }
    #pragma unroll
    for (int i = 0; i < 2; i++)
        #pragma unroll
        for (int j = 0; j < 8; j++)
            #pragma unroll
            for (int r = 0; r < 4; r++) acc[i][j][r] -= mvv[j];

    const int wgrp = (wave >> 2) * 4;
    float M[2][4];
    #pragma unroll
    for (int i = 0; i < 2; i++)
        #pragma unroll
        for (int r = 0; r < 4; r++) {
            float v = acc[i][0][r];
            #pragma unroll
            for (int j = 1; j < 8; j++) v = fmaxf(v, acc[i][j][r]);
            #pragma unroll
            for (int d = 1; d <= 8; d <<= 1) v = fmaxf(v, __shfl_xor(v, d));
            if (l16 == 0) redm[wave][i * 16 + quad * 4 + r] = v;
        }
    __syncthreads();
    #pragma unroll
    for (int i = 0; i < 2; i++)
        #pragma unroll
        for (int r = 0; r < 4; r++) {
            int rl = i * 16 + quad * 4 + r;
            float v = redm[wgrp][rl];
            #pragma unroll
            for (int k = 1; k < 4; k++) v = fmaxf(v, redm[wgrp + k][rl]);
            M[i][r] = v;
        }

    float psum[2][4] = {};
    #pragma unroll
    for (int i = 0; i < 2; i++)
        #pragma unroll
        for (int j = 0; j < 8; j++)
            #pragma unroll
            for (int r = 0; r < 4; r++) {
                float e = __expf(acc[i][j][r] - M[i][r]);
                acc[i][j][r] = e;
                psum[i][r] += e;
            }
    #pragma unroll
    for (int i = 0; i < 2; i++)
        #pragma unroll
        for (int r = 0; r < 4; r++) {
            float v = psum[i][r];
            #pragma unroll
            for (int d = 1; d <= 8; d <<= 1) v += __shfl_xor(v, d);
            if (l16 == 0) reds[wave][i * 16 + quad * 4 + r] = v;
        }
    __syncthreads();
    #pragma unroll
    for (int i = 0; i < 2; i++)
        #pragma unroll
        for (int r = 0; r < 4; r++) {
            int rl = i * 16 + quad * 4 + r;
            float s = reds[wgrp][rl] + reds[wgrp + 1][rl]
                    + reds[wgrp + 2][rl] + reds[wgrp + 3][rl];
            M[i][r] = 1.f / s;
        }

    #pragma unroll
    for (int i = 0; i < 2; i++)
        #pragma unroll
        for (int r = 0; r < 4; r++) {
            int gm = m0 + wm + i * 16 + quad * 4 + r;
            if (gm < L) {
                unsigned short* orow = att_h + ((long)b * L + gm) * 512;
                #pragma unroll
                for (int j = 0; j < 8; j++)
                    orow[wn + j * 16 + l16] = f2h(acc[i][j][r] * M[i][r]);
            }
        }
}

// ---------------------------------------------------------------------------
// att_pv: PV GEMM, pipelined (round-6, verified). Unchanged.
// ---------------------------------------------------------------------------
__global__ __launch_bounds__(512, 4) void att_pv(
    const unsigned short* __restrict__ att_h,   // [64*141][512] f16
    const unsigned short* __restrict__ text_hT, // [64][256][512] f16
    unsigned short* __restrict__ feat_h)        // [64][141*256] f16
{
    __shared__ unsigned short As[2 * 64 * 64];  // 16 KB: [pa][row][kchunk]
    __shared__ unsigned short Bs[3][256 * 32];  // 48 KB
    const int tid  = threadIdx.x;
    const int wave = tid >> 6, lane = tid & 63;
    const int quad = lane >> 4, l16 = lane & 15;
    const int m0 = blockIdx.x * 64;
    const int b  = blockIdx.y;
    const int wm = (wave >> 2) * 32;
    const int wn = (wave & 3) * 64;

    int arow = m0 + wave * 8 + (lane >> 3); if (arow > L - 1) arow = L - 1;
    const int asc = (lane & 7) ^ (lane >> 3);           // src chunk swizzle
    const unsigned short* aSrc = att_h + ((long)b * L + arow) * 512 + asc * 8;
    const int aDst = wave * 512;                        // shorts (1 KB/wave)
    auto issueA = [&](int ka, int pa) {                 // ka in 64-k units
        gload_lds16(aSrc + ka * 64, &As[pa * 4096 + aDst]);
    };

    const int bsc = (lane & 3) ^ ((lane >> 3) & 3);
    const long bOff0 = ((long)b * 256 + wave * 32 + (lane >> 2)) * 512 + bsc * 8;
    const long bOff1 = bOff0 + 16 * 512;
    const int bDst0 = (wave * 32) * 32, bDst1 = bDst0 + 16 * 32;
    auto issueB = [&](int kt, int pb) {
        gload_lds16(text_hT + bOff0 + kt * 32, &Bs[pb][bDst0]);
        gload_lds16(text_hT + bOff1 + kt * 32, &Bs[pb][bDst1]);
    };

    int aro[2], axm[2], bro[4];
    #pragma unroll
    for (int i = 0; i < 2; i++) {
        int r = wm + i * 16 + l16;
        aro[i] = r * 64; axm[i] = r & 7;
    }
    #pragma unroll
    for (int j = 0; j < 4; j++) {
        int n = wn + j * 16 + l16;
        bro[j] = n * 32 + ((quad ^ ((n >> 1) & 3)) << 3);
    }

    issueA(0, 0);
    issueB(0, 0);
    issueB(1, 1);
    asm volatile("s_waitcnt vmcnt(2)" ::: "memory");    // A(0)+B(0) landed
    asm volatile("s_barrier" ::: "memory");

    f32x4 acc[2][4] = {};
    #pragma unroll 1
    for (int t = 0; t < 16; t++) {
        const int pa = (t >> 1) & 1, pr = t % 3, sub = t & 1;
        f16x8 a[2], bfr[4];
        const unsigned short* ab = &As[pa * 4096];
        #pragma unroll
        for (int i = 0; i < 2; i++)
            a[i] = *(const f16x8*)&ab[aro[i] + (((sub * 4 + quad) ^ axm[i]) << 3)];
        const unsigned short* bb = &Bs[pr][0];
        #pragma unroll
        for (int j = 0; j < 4; j++) bfr[j] = *(const f16x8*)&bb[bro[j]];
        #pragma unroll
        for (int i = 0; i < 2; i++)
            #pragma unroll
            for (int j = 0; j < 4; j++)
                acc[i][j] = __builtin_amdgcn_mfma_f32_16x16x32_f16(
                    a[i], bfr[j], acc[i][j], 0, 0, 0);
        if (t < 15) {
            if (sub == 0) {
                int ka = (t >> 1) + 1; if (ka > 7) ka = 7;
                issueA(ka, pa ^ 1);
            }
            int kb = t + 2; if (kb > 15) kb = 15;
            issueB(kb, (t + 2) % 3);
            if (sub == 0) {
                asm volatile("s_waitcnt vmcnt(3)" ::: "memory");
            } else {
                asm volatile("s_waitcnt vmcnt(2)" ::: "memory");
            }
            asm volatile("s_barrier" ::: "memory");
        }
    }
    asm volatile("s_waitcnt vmcnt(0)" ::: "memory");

    #pragma unroll
    for (int i = 0; i < 2; i++)
        #pragma unroll
        for (int j = 0; j < 4; j++)
            #pragma unroll
            for (int r = 0; r < 4; r++) {
                int gm = m0 + wm + i * 16 + quad * 4 + r;
                if (gm < L) {
                    int h = wn + j * 16 + l16;
                    feat_h[(long)b * (L * H) + (long)gm * 256 + h] =
                        f2h(acc[i][j][r]);
                }
            }
}

// ---------------------------------------------------------------------------
// MFMA fp16 GEMM (EPI4 only). Tile = (32*IM) x 128, BK=32, 4 waves.
// ---------------------------------------------------------------------------
template<int EPI, bool CONVA, int IM>
__global__ __launch_bounds__(256) void gemm_mfma(
    const void* __restrict__ Aptr, int lda, long strA,
    const unsigned short* __restrict__ Bp, int ldb, long strB,
    float* __restrict__ C, int ldc, long strC,
    int M, int N, int K,
    const float* __restrict__ bias,
    const int* __restrict__ tokens,
    unsigned short* __restrict__ outH,
    unsigned short* __restrict__ outHT,
    int kChunk)
{
    __shared__ unsigned short A_s[32 * IM * 32];
    __shared__ unsigned short B_s[128 * 32];
    const int tid  = threadIdx.x;
    const int wave = tid >> 6, lane = tid & 63;
    const int quad = lane >> 4, l16 = lane & 15;
    const int bz = blockIdx.z;
    const int m0 = blockIdx.y * (32 * IM), n0 = blockIdx.x * 128;
    const int wm = (wave & 1) * (16 * IM), wn = (wave >> 1) * 64;

    long aBase, bBase;
    int kBeg, kEnd;
    if (EPI == 4) { aBase = 0; bBase = 0; kBeg = bz * kChunk; kEnd = kBeg + kChunk; }
    else { aBase = (long)bz * strA; bBase = (long)bz * strB; kBeg = 0; kEnd = K; }

    f32x4 acc[IM][4] = {};

    for (int k0 = kBeg; k0 < kEnd; k0 += 32) {
        if (CONVA) {
            const float* Af = (const float*)Aptr + aBase;
            #pragma unroll
            for (int it = 0; it < IM; it++) {
                int idx = it * 256 + tid;
                int row = idx >> 3, col4 = idx & 7;
                int gm = m0 + row; if (gm > M - 1) gm = M - 1;
                float4 v = *(const float4*)(Af + (long)gm * lda + k0 + col4 * 4);
                unsigned int p0 = f2h(v.x) | ((unsigned int)f2h(v.y) << 16);
                unsigned int p1 = f2h(v.z) | ((unsigned int)f2h(v.w) << 16);
                *(uint2*)&A_s[row * 32 + col4 * 4] = make_uint2(p0, p1);
            }
        } else {
            const unsigned short* Ab = (const unsigned short*)Aptr + aBase;
            #pragma unroll
            for (int t = 0; t < IM / 2; t++) {
                int rowb = wave * (8 * IM) + t * 16;
                int gm = m0 + rowb + (lane >> 2); if (gm > M - 1) gm = M - 1;
                gload_lds16(Ab + (long)gm * lda + k0 + (lane & 3) * 8,
                            &A_s[rowb * 32]);
            }
        }
        #pragma unroll
        for (int t = 0; t < 2; t++) {
            int rowb = wave * 32 + t * 16;
            int gn = n0 + rowb + (lane >> 2); if (gn > N - 1) gn = N - 1;
            gload_lds16(Bp + bBase + (long)gn * ldb + k0 + (lane & 3) * 8,
                        &B_s[rowb * 32]);
        }
        __syncthreads();
        f16x8 a[IM], b[4];
        #pragma unroll
        for (int i = 0; i < IM; i++)
            a[i] = *(const f16x8*)&A_s[(wm + i * 16 + l16) * 32 + quad * 8];
        #pragma unroll
        for (int j = 0; j < 4; j++)
            b[j] = *(const f16x8*)&B_s[(wn + j * 16 + l16) * 32 + quad * 8];
        #pragma unroll
        for (int i = 0; i < IM; i++)
            #pragma unroll
            for (int j = 0; j < 4; j++)
                acc[i][j] = __builtin_amdgcn_mfma_f32_16x16x32_f16(
                    a[i], b[j], acc[i][j], 0, 0, 0);
        __syncthreads();
    }

    #pragma unroll
    for (int i = 0; i < IM; i++) {
        #pragma unroll
        for (int j = 0; j < 4; j++) {
            #pragma unroll
            for (int r = 0; r < 4; r++) {
                int ml = wm + i * 16 + quad * 4 + r;
                int nl = wn + j * 16 + l16;
                int gm = m0 + ml, gn = n0 + nl;
                if (gm >= M || gn >= N) continue;
                float v = acc[i][j][r];
                if (EPI == 2) {
                    int tok = tokens[(long)bz * 512 + gn];
                    if (tok == 0 || tok == 101 || tok == 102) v -= 1e30f;
                    C[(long)bz * strC + (long)gm * ldc + gn] = v;
                } else if (EPI == 3) {
                    outH[(long)bz * strC + (long)gm * ldc + gn] = f2h(v);
                } else { // EPI 4: partial K-slice
                    C[(long)bz * strC + (long)gm * ldc + gn] = v;
                }
            }
        }
    }
}

// out = sigmoid(bias + sum of nz partial K-slices)
__global__ __launch_bounds__(256) void out_final(
    const float* __restrict__ acc, const float* __restrict__ ob,
    float* __restrict__ out, int total, int nz)
{
    int i = blockIdx.x * 256 + threadIdx.x;
    if (i >= total) return;
    float v = ob[i % L];
    #pragma unroll 4
    for (int z = 0; z < nz; z++) v += acc[(long)z * total + i];
    out[i] = sigf(v);
}

extern "C" void kernel_launch(void* const* d_in, const int* in_sizes, int n_in,
                              void* d_out, int out_size, void* d_ws, size_t ws_size,
                              hipStream_t stream)
{
    (void)in_sizes; (void)n_in; (void)out_size; (void)ws_size;
    const int*   inputs      = (const int*)d_in[0];
    const float* text_hidden = (const float*)d_in[1];
    const float* label_enc   = (const float*)d_in[2];
    const float* w12   = (const float*)d_in[3];
    const float* w23   = (const float*)d_in[4];
    const float* fre12 = (const float*)d_in[5];
    const float* fre23 = (const float*)d_in[6];
    const float* wi1_W = (const float*)d_in[7],  *wi1_b = (const float*)d_in[8];
    const float* wf1_W = (const float*)d_in[9],  *wf1_b = (const float*)d_in[10];
    const float* wo1_W = (const float*)d_in[11], *wo1_b = (const float*)d_in[12];
    const float* wu1_W = (const float*)d_in[13], *wu1_b = (const float*)d_in[14];
    const float* wi2_W = (const float*)d_in[15], *wi2_b = (const float*)d_in[16];
    const float* wf2_W = (const float*)d_in[17], *wf2_b = (const float*)d_in[18];
    const float* wo2_W = (const float*)d_in[19], *wo2_b = (const float*)d_in[20];
    const float* wu2_W = (const float*)d_in[21], *wu2_b = (const float*)d_in[22];
    const float* ui1_W = (const float*)d_in[23], *uf1_W = (const float*)d_in[24];
    const float* uo1_W = (const float*)d_in[25], *uu1_W = (const float*)d_in[26];
    const float* ui2_W = (const float*)d_in[27], *uf2_W = (const float*)d_in[28];
    const float* uo2_W = (const float*)d_in[29], *uu2_W = (const float*)d_in[30];
    const float* mix_W = (const float*)d_in[31], *mix_b = (const float*)d_in[32];
    const float* tt_W  = (const float*)d_in[33], *tt_b  = (const float*)d_in[34];
    const float* Amat  = (const float*)d_in[35], *Wp    = (const float*)d_in[36];
    const float* out_W = (const float*)d_in[37], *out_b = (const float*)d_in[38];
    float* out = (float*)d_out;

    // ---- workspace (float units, 16B-aligned chunks) ----
    float* ws = (float*)d_ws;
    float* att     = ws; ws += (long)B * L * S;                                 // (unused, layout kept)
    unsigned short* text_h  = (unsigned short*)ws; ws += (long)B * S * H / 2;   // [b*s][h]
    unsigned short* text_hT = (unsigned short*)ws; ws += (long)B * S * H / 2;   // [b][h][s]
    unsigned short* att_h   = (unsigned short*)ws; ws += (long)B * L * S / 2;
    unsigned short* tt_Wt   = (unsigned short*)ws; ws += 768 * H / 2;           // tiled [24][256][32]
    unsigned short* le_h    = (unsigned short*)ws; ws += L * H / 2 + 4;
    unsigned short* out_Wh  = (unsigned short*)ws; ws += (long)L * 36096 / 2;   // [n][k]
    unsigned short* feat_h  = (unsigned short*)ws; ws += (long)B * L * H / 2;   // [b][l*256+h]
    float* outacc = ws; ws += (long)B * L * 141;                                // partial K-slices
    float* G    = ws; ws += 7 * 141 * 256;
    float* tmpP = ws; ws += L * H;
    float* wv2f = ws; ws += N3 * H;
    float* wv1f = ws; ws += N2 * H;
    float* h11  = ws; ws += N1 * H;  float* c11  = ws; ws += N1 * H;
    float* h21  = ws; ws += N2 * H;  float* c21  = ws; ws += N2 * H;
    float* h21t = ws; ws += N2 * H;  float* c21p = ws; ws += N2 * H;
    float* h31  = ws; ws += N3 * H;  float* h31t = ws; ws += N3 * H;
    float* c31p = ws; ws += N3 * H;
    float* h32  = ws; ws += N3 * H;  float* c32  = ws; ws += N3 * H;
    float* h22  = ws; ws += N2 * H;  float* c22  = ws; ws += N2 * H;
    float* h22t = ws; ws += N2 * H;  float* fcb  = ws; ws += N3 * H;
    float* h12  = ws; ws += N1 * H;  float* h12t = ws; ws += N1 * H;
    float* fc2b = ws; ws += N2 * H;
    (void)att;

    // 1. prep: tt_W -> f16 tiled  +  out_W -> fp16 [141][36096]
    prep<<<24 + 564 * 3, 256, 0, stream>>>(tt_W, tt_Wt, out_W, out_Wh);
    // 2. text = tanh(text_hidden @ tt_W + b) -> fp16 both layouts (128-m tile)
    text_gemm4<<<256, 1024, 0, stream>>>(
        text_hidden, tt_Wt, tt_b, text_h, text_hT);
    // 3. gate pre-activations G + independent two-stage rows (fused)
    gates_pre<<<28 * 141 + 4 * 273, 256, 0, stream>>>(label_enc,
        wi1_W, wf1_W, wo1_W, wu1_W, wi2_W, wo2_W, wu2_W,
        wi1_b, wf1_b, wo1_b, wu1_b, wi2_b, wo2_b, wu2_b,
        Amat, w23, w12, Wp, wf2_W, G, tmpP, wv2f, wv1f);
    // 4-8. label chain
    ew1<<<107, 256, 0, stream>>>(G, h11, c11, h32, c32);
    chain_mm<<<dim3(4, 200), 256, 0, stream>>>(0, w12, w23, fre23, fre12,
        h11, c11, h32, h21, c21, h22, wv2f, wv1f, wf2_b, uf2_W, c32, c22,
        h21t, c21p, h22t, fcb, h31t, c31p, h12t, fc2b);
    lstm_fused<<<dim3(4, 68), 256, 0, stream>>>(0, G,
        h21t, c21p, h22t, fcb, h31t, c31p, h12t, fc2b, w23, w12,
        ui1_W, uf1_W, uo1_W, uu1_W, ui2_W, uo2_W, uu2_W,
        h21, c21, h22, c22, h31, h12);
    chain_mm<<<dim3(4, 239), 256, 0, stream>>>(1, w12, w23, fre23, fre12,
        h11, c11, h32, h21, c21, h22, wv2f, wv1f, wf2_b, uf2_W, c32, c22,
        h21t, c21p, h22t, fcb, h31t, c31p, h12t, fc2b);
    lstm_fused<<<dim3(4, 107), 256, 0, stream>>>(1, G,
        h21t, c21p, h22t, fcb, h31t, c31p, h12t, fc2b, w23, w12,
        ui1_W, uf1_W, uo1_W, uu1_W, ui2_W, uo2_W, uu2_W,
        h21, c21, h22, c22, h31, h12);
    mix_mm<<<dim3(4, 141), 256, 0, stream>>>(h11, h12, h21, h22, h31, h32,
        tmpP, mix_W, mix_b, le_h);
    // 9. logits + mask + softmax fused -> att_h f16
    att_logits2<<<dim3(3, 64), 512, 0, stream>>>(
        le_h, text_h, inputs, att_h);
    // 10. feat (fp16 out, [b][l*256+h]) — pipelined att_pv
    att_pv<<<dim3(3, 64), 512, 0, stream>>>(att_h, text_hT, feat_h);
    // 11. out-head: K-split MFMA -> 141 partial slices (no atomics)
    gemm_mfma<4, false, 2><<<dim3(2, 1, 141), 256, 0, stream>>>(
        feat_h, L * H, 0, out_Wh, L * H, 0, outacc, L, (long)B * L,
        B, L, L * H, nullptr, nullptr, nullptr, nullptr, 256);
    // 12. reduce + sigmoid + bias
    out_final<<<(B * L + 255) / 256, 256, 0, stream>>>(outacc, out_b, out, B * L, 141);
}

// Round 10
// 426.482 us; speedup vs baseline: 1.0389x; 1.0389x over previous
//
#include <hip/hip_runtime.h>
#include <math.h>

// Problem constants
static constexpr int H = 256, L = 141, N1 = 9, N2 = 34, N3 = 98;
static constexpr int B = 64, S = 512;

typedef __attribute__((ext_vector_type(8))) _Float16 f16x8;
typedef __attribute__((ext_vector_type(4))) float f32x4;

__device__ inline unsigned short f2h(float x) {
    _Float16 h = (_Float16)x;
    return __builtin_bit_cast(unsigned short, h);
}
__device__ inline float sigf(float x) { return 1.f / (1.f + __expf(-x)); }

__device__ inline void gload_lds16(const void* g, void* l) {
    __builtin_amdgcn_global_load_lds(
        (const __attribute__((address_space(1))) void*)g,
        (__attribute__((address_space(3))) void*)l, 16, 0, 0);
}

// ---------------------------------------------------------------------------
// prep_gates: fuses prep (conv_ttW 24 + out_W transpose 1692 blocks) with
// gates_pre (gate_pre 3948 + pre2 1092 blocks). All four job families are
// mutually independent (read only kernel inputs / write disjoint buffers),
// so block-range dispatch needs no barrier. Bodies verbatim.
// ---------------------------------------------------------------------------
__global__ __launch_bounds__(256) void prep_gates(
    const float* __restrict__ ttW, unsigned short* __restrict__ Bt,
    const float* __restrict__ outW, unsigned short* __restrict__ outWh,
    const float* __restrict__ le,
    const float* W0, const float* W1, const float* W2, const float* W3,
    const float* W4, const float* W5, const float* W6,
    const float* b0, const float* b1, const float* b2, const float* b3,
    const float* b4, const float* b5, const float* b6,
    const float* __restrict__ Amat, const float* __restrict__ w23,
    const float* __restrict__ w12, const float* __restrict__ Wp,
    const float* __restrict__ wf2_W,
    float* __restrict__ G, float* __restrict__ tmpP,
    float* __restrict__ wv2f, float* __restrict__ wv1f)
{
    __shared__ float sf[4112];                   // union: 16448 B
    unsigned short* su = (unsigned short*)sf;
    const int tid = threadIdx.x;
    const int bx = blockIdx.x;
    const int nl = tid & 63, ks = tid >> 6;
    if (bx < 24) {
        // ---- conv_ttW body: Tl[r][c] = su[r*257+c] ----
        const int t = bx;
        #pragma unroll
        for (int p = 0; p < 32; p++) {
            int lin = p * 256 + tid;
            int r = lin >> 8, c = lin & 255;
            su[r * 257 + c] = f2h(ttW[(long)(t * 32 + r) * 256 + c]);
        }
        __syncthreads();
        unsigned short v[32];
        #pragma unroll
        for (int kin = 0; kin < 32; kin++) v[kin] = su[kin * 257 + tid];
        uint4* dst = (uint4*)(Bt + ((long)t * 256 + tid) * 32);
        #pragma unroll
        for (int q = 0; q < 4; q++) dst[q] = ((const uint4*)v)[q];
    } else if (bx < 24 + 1692) {
        // ---- transp_t64 body for out_W (R=36096, C=141): T2 = su[c*65+r] ----
        const int u = bx - 24;
        const int r0 = (u % 564) * 64, c0 = (u / 564) * 64;
        const int R = 36096, C = 141;
        #pragma unroll
        for (int p = 0; p < 16; p++) {
            int lin = p * 256 + tid;
            int r = lin >> 6, c = lin & 63;
            int gc = c0 + c;
            float v = (gc < C) ? outW[(long)(r0 + r) * C + gc] : 0.f;
            su[c * 65 + r] = f2h(v);
        }
        __syncthreads();
        #pragma unroll
        for (int p = 0; p < 16; p++) {
            int lin = p * 256 + tid;
            int c = lin >> 6, r = lin & 63;
            if (c0 + c < C)
                outWh[(long)(c0 + c) * R + r0 + r] = su[c * 65 + r];
        }
    } else if (bx < 24 + 1692 + 3948) {
        // ---- gate_pre body ----
        const int u = bx - (24 + 1692);
        const int bb = u % 28, m = u / 28;
        const int j = bb >> 2, x = bb & 3, n = x * 64 + nl;
        float* ls = sf; float* red = sf + 256;
        ls[tid] = le[(long)m * 256 + tid];
        __syncthreads();
        const float *W, *bb2;
        switch (j) {
            case 0: W = W0; bb2 = b0; break;  case 1: W = W1; bb2 = b1; break;
            case 2: W = W2; bb2 = b2; break;  case 3: W = W3; bb2 = b3; break;
            case 4: W = W4; bb2 = b4; break;  case 5: W = W5; bb2 = b5; break;
            default: W = W6; bb2 = b6;
        }
        float a0 = 0, a1 = 0, a2 = 0, a3 = 0;
        for (int k = ks; k + 12 < 256; k += 16) {
            long o = (long)k * 256 + n;
            a0 += ls[k] * W[o];        a1 += ls[k + 4] * W[o + 1024];
            a2 += ls[k + 8] * W[o + 2048]; a3 += ls[k + 12] * W[o + 3072];
        }
        red[tid] = a0 + a1 + a2 + a3;
        __syncthreads();
        if (ks == 0)
            G[((long)j * 141 + m) * 256 + n] =
                red[nl] + red[64 + nl] + red[128 + nl] + red[192 + nl] + bb2[n];
    } else {
        // ---- pre2 body ----
        const int u = bx - (24 + 1692 + 3948);
        const int x = u % 4, y = u / 4, n = x * 64 + nl;
        int job, m, K1;
        if (y < 141)      { job = 0; m = y;       K1 = 141; }
        else if (y < 239) { job = 1; m = y - 141; K1 = 34; }
        else              { job = 2; m = y - 239; K1 = 9; }
        float* cs = sf; float* t = sf + 256; float* red = sf + 512;
        if (tid < K1)
            cs[tid] = (job == 0) ? Amat[(long)m * 141 + tid]
                    : (job == 1) ? w23[(long)tid * 98 + m]
                                 : w12[(long)tid * 34 + m];
        __syncthreads();
        const float* s1 = (job == 1) ? le + 9 * 256 : le;
        float acc = 0;
        #pragma unroll 4
        for (int k = 0; k < K1; k++) acc += cs[k] * s1[(long)k * 256 + tid];
        t[tid] = acc;
        __syncthreads();
        const float* W = (job == 0) ? Wp : wf2_W;
        float a0 = 0, a1 = 0, a2 = 0, a3 = 0;
        for (int k = ks; k + 12 < 256; k += 16) {
            long o = (long)k * 256 + n;
            a0 += t[k] * W[o];        a1 += t[k + 4] * W[o + 1024];
            a2 += t[k + 8] * W[o + 2048]; a3 += t[k + 12] * W[o + 3072];
        }
        red[tid] = a0 + a1 + a2 + a3;
        __syncthreads();
        if (ks == 0) {
            float tot = red[nl] + red[64 + nl] + red[128 + nl] + red[192 + nl];
            if (job == 0)      tmpP[(long)m * 256 + n] = fmaxf(tot, 0.f);
            else if (job == 1) wv2f[(long)m * 256 + n] = tot;
            else               wv1f[(long)m * 256 + n] = tot;
        }
    }
}

// ---------------------------------------------------------------------------
// text_gemm3: pipelined LDS-staged GEMM (round-3/8, proven best). Unchanged.
// ---------------------------------------------------------------------------
__global__ __launch_bounds__(512, 4) void text_gemm3(
    const float* __restrict__ Af,            // [32768][768] fp32
    const unsigned short* __restrict__ Bt,   // [24][256][32] f16 tiled
    const float* __restrict__ bias,          // [256]
    unsigned short* __restrict__ outH,       // [32768][256] fp16
    unsigned short* __restrict__ outHT)      // [64][256][512] fp16
{
    __shared__ unsigned short smem[28672];   // 57344 B
    unsigned short* As = smem;               // 2 x [64][32]  (4096 shorts)
    unsigned short* Bs = smem + 4096;        // 3 x [256][32] (24576 shorts)
    unsigned short* T  = smem;               // epilogue alias: [256][72]

    const int tid  = threadIdx.x;
    const int wave = tid >> 6, lane = tid & 63;
    const int quad = lane >> 4, l16 = lane & 15;
    const int m0 = blockIdx.x * 64;
    const int wm = (wave >> 2) * 32;         // 2 m-groups
    const int wn = (wave & 3) * 64;          // 4 n-groups

    const int arow = tid >> 3;               // 0..63
    const int ac16 = tid & 7;                // 0..7 (16B fp32 chunks)
    const float* aSrc = Af + (long)(m0 + arow) * 768 + ac16 * 4;
    const int ac8d = ac16 ^ ((arow & 3) << 1);
    const int aWoff = arow * 32 + ac8d * 4;  // shorts

    const int bsc = (lane & 3) ^ ((lane >> 3) & 3);     // src chunk16 swizzle
    const long bSrcOff0 = (long)(wave * 32 + (lane >> 2)) * 32 + bsc * 8;
    const long bSrcOff1 = bSrcOff0 + 16 * 32;
    const int bDst0 = (wave * 32) * 32, bDst1 = (wave * 32 + 16) * 32;

    int aro[2], bro[4];
    #pragma unroll
    for (int i = 0; i < 2; i++) {
        int r = wm + i * 16 + l16;
        aro[i] = r * 32 + ((quad * 2) ^ ((r & 3) << 1)) * 4;
    }
    #pragma unroll
    for (int j = 0; j < 4; j++) {
        int n = wn + j * 16 + l16;
        bro[j] = n * 32 + ((quad ^ ((n >> 1) & 3)) << 3);
    }

    f32x4 acc[2][4] = {};
    float4 ar0, ar1;

    auto issueB = [&](int kt, int pb) {
        const unsigned short* src = Bt + (long)kt * 8192;
        unsigned short* d = Bs + pb * 8192;
        gload_lds16(src + bSrcOff0, d + bDst0);
        gload_lds16(src + bSrcOff1, d + bDst1);
    };
    auto writeA = [&](const float4& v, int pa) {
        unsigned int p0 = f2h(v.x) | ((unsigned int)f2h(v.y) << 16);
        unsigned int p1 = f2h(v.z) | ((unsigned int)f2h(v.w) << 16);
        *(uint2*)&As[pa * 2048 + aWoff] = make_uint2(p0, p1);
    };

    ar0 = *(const float4*)(aSrc + 0 * 32);
    issueB(0, 0);
    ar1 = *(const float4*)(aSrc + 1 * 32);
    issueB(1, 1);
    asm volatile("s_waitcnt vmcnt(5)" ::: "memory");   // A(0) landed
    writeA(ar0, 0);
    asm volatile("s_waitcnt vmcnt(3)" ::: "memory");   // B(0) landed (own)
    asm volatile("s_waitcnt lgkmcnt(0)" ::: "memory");
    asm volatile("s_barrier" ::: "memory");

    auto body = [&](int t, float4& arIn, float4& arOut, int pa, int pr) {
        int kt2 = (t + 2 <= 23) ? t + 2 : 23;
        arOut = *(const float4*)(aSrc + kt2 * 32);
        f16x8 a[2], b[4];
        const unsigned short* ab = As + pa * 2048;
        const unsigned short* bb = Bs + pr * 8192;
        #pragma unroll
        for (int i = 0; i < 2; i++) a[i] = *(const f16x8*)&ab[aro[i]];
        #pragma unroll
        for (int j = 0; j < 4; j++) b[j] = *(const f16x8*)&bb[bro[j]];
        #pragma unroll
        for (int i = 0; i < 2; i++)
            #pragma unroll
            for (int j = 0; j < 4; j++)
                acc[i][j] = __builtin_amdgcn_mfma_f32_16x16x32_f16(
                    a[i], b[j], acc[i][j], 0, 0, 0);
        asm volatile("s_waitcnt vmcnt(3)" ::: "memory");
        writeA(arIn, pa ^ 1);
        int pw = pr + 2; if (pw >= 3) pw -= 3;
        issueB(kt2, pw);
        asm volatile("s_waitcnt vmcnt(3)" ::: "memory");
        asm volatile("s_waitcnt lgkmcnt(0)" ::: "memory");
        asm volatile("s_barrier" ::: "memory");
    };

    int pr = 0;
    #pragma unroll 1
    for (int t = 0; t < 24; t += 2) {
        body(t,     ar1, ar0, 0, pr);
        int pr1 = pr + 1; if (pr1 >= 3) pr1 -= 3;
        body(t + 1, ar0, ar1, 1, pr1);
        pr = pr1 + 1; if (pr >= 3) pr -= 3;
    }
    asm volatile("s_waitcnt vmcnt(0)" ::: "memory");
    __syncthreads();

    float bv[4];
    #pragma unroll
    for (int j = 0; j < 4; j++) bv[j] = bias[wn + j * 16 + l16];

    #pragma unroll
    for (int i = 0; i < 2; i++) {
        #pragma unroll
        for (int j = 0; j < 4; j++) {
            const int mlb = wm + i * 16 + quad * 4;
            const int n   = wn + j * 16 + l16;
            unsigned short hv[4];
            #pragma unroll
            for (int r = 0; r < 4; r++) {
                float v = tanhf(acc[i][j][r] + bv[j]);
                hv[r] = f2h(v);
                outH[(long)(m0 + mlb + r) * 256 + n] = hv[r];
            }
            uint2 p;
            p.x = hv[0] | ((unsigned int)hv[1] << 16);
            p.y = hv[2] | ((unsigned int)hv[3] << 16);
            *(uint2*)&T[n * 72 + mlb] = p;
        }
    }
    __syncthreads();
    {
        const int bb2 = m0 >> 9, s0 = m0 & 511;
        const int n = tid >> 1, half = tid & 1;
        const uint4* src = (const uint4*)&T[n * 72 + half * 32];
        uint4* dst = (uint4*)&outHT[((long)bb2 * 256 + n) * 512 + s0 + half * 32];
        dst[0] = src[0]; dst[1] = src[1];
        dst[2] = src[2]; dst[3] = src[3];
    }
}

// L1: elementwise gates -> h11,c11 (9r) and h32,c32 (98r). grid(107)
__global__ __launch_bounds__(256) void ew1(
    const float* __restrict__ G, float* __restrict__ h11, float* __restrict__ c11,
    float* __restrict__ h32, float* __restrict__ c32)
{
    int y = blockIdx.x, n = threadIdx.x;
    if (y < 9) {
        int m = y;
        float iv = sigf(G[(0L * 141 + m) * 256 + n]);
        float ov = sigf(G[(2L * 141 + m) * 256 + n]);
        float uv = tanhf(G[(3L * 141 + m) * 256 + n]);
        float cv = iv * uv;
        c11[m * 256 + n] = cv; h11[m * 256 + n] = ov * tanhf(cv);
    } else {
        int r = y - 9, grow = 43 + r;
        float iv = sigf(G[(4L * 141 + grow) * 256 + n]);
        float ov = sigf(G[(5L * 141 + grow) * 256 + n]);
        float uv = tanhf(G[(6L * 141 + grow) * 256 + n]);
        float cv = iv * uv;
        c32[r * 256 + n] = cv; h32[r * 256 + n] = ov * tanhf(cv);
    }
}

// chain_mm: fused sparse/row matmuls.
__global__ __launch_bounds__(256) void chain_mm(int phase,
    const float* __restrict__ w12, const float* __restrict__ w23,
    const float* __restrict__ fre23, const float* __restrict__ fre12,
    const float* __restrict__ h11, const float* __restrict__ c11,
    const float* __restrict__ h32,
    const float* __restrict__ h21, const float* __restrict__ c21,
    const float* __restrict__ h22,
    const float* __restrict__ wv2f, const float* __restrict__ wv1f,
    const float* __restrict__ wf2_b, const float* __restrict__ uf2_W,
    const float* __restrict__ c32, const float* __restrict__ c22,
    float* __restrict__ h21t, float* __restrict__ c21p,
    float* __restrict__ h22t, float* __restrict__ fcb,
    float* __restrict__ h31t, float* __restrict__ c31p,
    float* __restrict__ h12t, float* __restrict__ fc2b)
{
    __shared__ float cs[256];
    __shared__ float red[256];
    const int x = blockIdx.x, y = blockIdx.y;
    const int tid = threadIdx.x, nl = tid & 63, ks = tid >> 6, n = x * 64 + nl;
    int job, m;
    if (phase == 0) {
        if (y < 34)       { job = 0; m = y; }
        else if (y < 68)  { job = 1; m = y - 34; }
        else if (y < 102) { job = 2; m = y - 68; }
        else              { job = 3; m = y - 102; }
    } else {
        if (y < 98)       { job = 0; m = y; }
        else if (y < 196) { job = 1; m = y - 98; }
        else if (y < 205) { job = 2; m = y - 196; }
        else              { job = 3; m = y - 205; }
    }
    if (job < 3) {
        int K; const float* src; float* dst;
        if (phase == 0) {
            K = (job == 2) ? 98 : 9;
            src = (job == 0) ? h11 : (job == 1) ? c11 : h32;
            dst = (job == 0) ? h21t : (job == 1) ? c21p : h22t;
            if (tid < K)
                cs[tid] = (job == 2) ? fre23[(long)m * 98 + tid]
                                     : w12[(long)tid * 34 + m];
        } else {
            K = 34;
            src = (job == 0) ? h21 : (job == 1) ? c21 : h22;
            dst = (job == 0) ? h31t : (job == 1) ? c31p : h12t;
            if (tid < K)
                cs[tid] = (job == 2) ? fre12[(long)m * 34 + tid]
                                     : w23[(long)tid * 98 + m];
        }
        __syncthreads();
        float a0 = 0;
        for (int k = ks; k < K; k += 4) a0 += cs[k] * src[(long)k * 256 + n];
        red[tid] = a0;
        __syncthreads();
        if (ks == 0)
            dst[(long)m * 256 + n] = red[nl] + red[64 + nl] + red[128 + nl] + red[192 + nl];
    } else {
        const float* row = (phase == 0) ? h32 + m * 256 : h22 + m * 256;
        const float* pre = (phase == 0) ? wv2f : wv1f;
        const float* cm  = (phase == 0) ? c32 : c22;
        float* dst       = (phase == 0) ? fcb : fc2b;
        cs[tid] = row[tid];
        __syncthreads();
        float a0 = 0, a1 = 0, a2 = 0, a3 = 0;
        for (int k = ks; k + 12 < 256; k += 16) {
            long o = (long)k * 256 + n;
            a0 += cs[k] * uf2_W[o];        a1 += cs[k + 4] * uf2_W[o + 1024];
            a2 += cs[k + 8] * uf2_W[o + 2048]; a3 += cs[k + 12] * uf2_W[o + 3072];
        }
        red[tid] = a0 + a1 + a2 + a3;
        __syncthreads();
        if (ks == 0) {
            float tot = red[nl] + red[64 + nl] + red[128 + nl] + red[192 + nl]
                      + pre[(long)m * 256 + n] + wf2_b[n];
            dst[(long)m * 256 + n] = sigf(tot) * cm[(long)m * 256 + n];
        }
    }
}

// lstm_fused: fused gate matmuls + elementwise.
__global__ __launch_bounds__(256) void lstm_fused(int phase,
    const float* __restrict__ G,
    const float* __restrict__ h21t, const float* __restrict__ c21p,
    const float* __restrict__ h22t, const float* __restrict__ fcb,
    const float* __restrict__ h31t, const float* __restrict__ c31p,
    const float* __restrict__ h12t, const float* __restrict__ fc2b,
    const float* __restrict__ w23, const float* __restrict__ w12,
    const float* __restrict__ ui1, const float* __restrict__ uf1,
    const float* __restrict__ uo1, const float* __restrict__ uu1,
    const float* __restrict__ ui2, const float* __restrict__ uo2,
    const float* __restrict__ uu2,
    float* __restrict__ h21, float* __restrict__ c21,
    float* __restrict__ h22, float* __restrict__ c22,
    float* __restrict__ h31, float* __restrict__ h12)
{
    __shared__ float hs[256];
    __shared__ float cs[128];
    __shared__ float red[1024];
    const int x = blockIdx.x, y = blockIdx.y;
    const int tid = threadIdx.x, nl = tid & 63, ks = tid >> 6, n = x * 64 + nl;
    bool modef; int m, grow, Kx = 0;
    const float *hrow, *U0, *U1, *U2, *U3 = nullptr, *Sx = nullptr, *cmod = nullptr;
    float *ho, *co = nullptr;
    if (phase == 0) {
        if (y < 34) { modef = true;  m = y;      grow = 9 + m;  hrow = h21t;
                      U0 = ui1; U1 = uf1; U2 = uo1; U3 = uu1; cmod = c21p; ho = h21; co = c21; }
        else        { modef = false; m = y - 34; grow = 9 + m;  hrow = h22t;
                      U0 = ui2; U1 = uo2; U2 = uu2; Sx = fcb; Kx = 98; ho = h22; co = c22;
                      if (tid < 98) cs[tid] = w23[(long)m * 98 + tid]; }
    } else {
        if (y < 98) { modef = true;  m = y;      grow = 43 + m; hrow = h31t;
                      U0 = ui1; U1 = uf1; U2 = uo1; U3 = uu1; cmod = c31p; ho = h31; co = nullptr; }
        else        { modef = false; m = y - 98; grow = m;      hrow = h12t;
                      U0 = ui2; U1 = uo2; U2 = uu2; Sx = fc2b; Kx = 34; ho = h12; co = nullptr;
                      if (tid < 34) cs[tid] = w12[(long)m * 34 + tid]; }
    }
    hs[tid] = hrow[(long)m * 256 + tid];
    __syncthreads();
    float a0 = 0, a1 = 0, a2 = 0, a3 = 0;
    if (modef) {
        for (int k = ks; k < 256; k += 4) {
            float xv = hs[k]; long o = (long)k * 256 + n;
            a0 += xv * U0[o]; a1 += xv * U1[o]; a2 += xv * U2[o]; a3 += xv * U3[o];
        }
    } else {
        for (int k = ks; k < 256; k += 4) {
            float xv = hs[k]; long o = (long)k * 256 + n;
            a0 += xv * U0[o]; a1 += xv * U1[o]; a2 += xv * U2[o];
        }
        for (int k = ks; k < Kx; k += 4) a3 += cs[k] * Sx[(long)k * 256 + n];
    }
    red[tid] = a0; red[256 + tid] = a1; red[512 + tid] = a2; red[768 + tid] = a3;
    __syncthreads();
    if (ks == 0) {
        float t0 = 0, t1 = 0, t2 = 0, t3 = 0;
        #pragma unroll
        for (int s2 = 0; s2 < 4; s2++) {
            t0 += red[s2 * 64 + nl];       t1 += red[256 + s2 * 64 + nl];
            t2 += red[512 + s2 * 64 + nl]; t3 += red[768 + s2 * 64 + nl];
        }
        if (modef) {
            float ti = t0 + G[(0L * 141 + grow) * 256 + n];
            float tf = t1 + G[(1L * 141 + grow) * 256 + n];
            float to = t2 + G[(2L * 141 + grow) * 256 + n];
            float tu = t3 + G[(3L * 141 + grow) * 256 + n];
            float cv = sigf(ti) * tanhf(tu) + sigf(tf) * cmod[(long)m * 256 + n];
            ho[(long)m * 256 + n] = sigf(to) * tanhf(cv);
            if (co) co[(long)m * 256 + n] = cv;
        } else {
            float ti = t0 + G[(4L * 141 + grow) * 256 + n];
            float to = t1 + G[(5L * 141 + grow) * 256 + n];
            float tu = t2 + G[(6L * 141 + grow) * 256 + n];
            float cv = sigf(ti) * tanhf(tu) + t3;
            ho[(long)m * 256 + n] = sigf(to) * tanhf(cv);
            if (co) co[(long)m * 256 + n] = cv;
        }
    }
}

// le_h[l] = fp16( [h?1(l) | h?2(l) | tmpP(l)] @ mix_W + mix_b ). grid (4,141)
__global__ __launch_bounds__(256) void mix_mm(
    const float* __restrict__ h11, const float* __restrict__ h12,
    const float* __restrict__ h21, const float* __restrict__ h22,
    const float* __restrict__ h31, const float* __restrict__ h32,
    const float* __restrict__ tmpP, const float* __restrict__ mix_W,
    const float* __restrict__ mix_b, unsigned short* __restrict__ le_h)
{
    __shared__ float ls[768];
    __shared__ float red[256];
    const int x = blockIdx.x, l = blockIdx.y;
    const int tid = threadIdx.x, nl = tid & 63, ks = tid >> 6, n = x * 64 + nl;
    const float *pa, *pb; int r;
    if (l < 9)       { pa = h11; pb = h12; r = l; }
    else if (l < 43) { pa = h21; pb = h22; r = l - 9; }
    else             { pa = h31; pb = h32; r = l - 43; }
    for (int j = tid; j < 768; j += 256) {
        float v;
        if (j < 256)      v = pa[r * 256 + j];
        else if (j < 512) v = pb[r * 256 + (j - 256)];
        else              v = tmpP[l * 256 + (j - 512)];
        ls[j] = v;
    }
    __syncthreads();
    float a0 = 0, a1 = 0, a2 = 0, a3 = 0;
    for (int k = ks; k + 12 < 768; k += 16) {
        long o = (long)k * 256 + n;
        a0 += ls[k] * mix_W[o];        a1 += ls[k + 4] * mix_W[o + 1024];
        a2 += ls[k + 8] * mix_W[o + 2048]; a3 += ls[k + 12] * mix_W[o + 3072];
    }
    red[tid] = a0 + a1 + a2 + a3;
    __syncthreads();
    if (ks == 0) {
        float tot = red[nl] + red[64 + nl] + red[128 + nl] + red[192 + nl] + mix_b[n];
        le_h[(long)l * 256 + n] = f2h(tot);
    }
}

// ---------------------------------------------------------------------------
// att_fused: logits + pad-mask + softmax (att_logits2, verified) + PV
// (att_pv, verified) fused in one kernel. Grid (3 l-tiles, 64 b), 512 thr.
//  Phase 1 (verbatim att_logits2): 64l x 512s logits, acc[2][8]; A = le_h
//    staged once; B dbuf'd with vmcnt(4) discipline; mask; exact softmax.
//  Bridge: P[64][512] f16 in LDS with 16B-chunk swizzle (c ^= row&7, G4's
//    row-reader fix); rows >= L zeroed. Aliases the (dead) logits buffers —
//    safe: every wave drains vmcnt(0) before the first softmax barrier.
//  Phase 2 (att_pv minus A-staging): V triple-buffered, vmcnt(2)/barrier;
//    A-frags read from P at k = t*32+quad*8 (same K-order -> accp bitwise
//    identical to att_pv). Saves att_h round-trip (18.4 MB) + 1 launch.
// ---------------------------------------------------------------------------
__global__ __launch_bounds__(512, 1) void att_fused(
    const unsigned short* __restrict__ le_h,    // [141][256] f16
    const unsigned short* __restrict__ text_h,  // [64*512][256] f16
    const unsigned short* __restrict__ text_hT, // [64][256][512] f16
    const int* __restrict__ tokens,             // [64][512]
    unsigned short* __restrict__ feat_h)        // [64][141*256] f16
{
    __shared__ unsigned short smem[57344];      // 114688 B
    __shared__ float redm[8][32];
    __shared__ float reds[8][32];
    unsigned short* A_s = smem;                 // logits: [64*256]  (32 KB)
    unsigned short* BsL = smem + 16384;         // logits: 2 x [512*32] (64 KB)
    unsigned short* P   = smem;                 // pv: [64][512] swizzled (64 KB)
    unsigned short* Vb  = smem + 32768;         // pv: 3 x [256*32] (48 KB)

    const int tid  = threadIdx.x;
    const int wave = tid >> 6, lane = tid & 63;
    const int quad = lane >> 4, l16 = lane & 15;
    const int m0 = blockIdx.x * 64;
    const int b  = blockIdx.y;
    const int wm = (wave >> 2) * 32;            // 2 m-groups
    const int wn = (wave & 3) * 128;            // logits: 4 n-groups x 128

    // ==================== Phase 1: logits + mask + softmax ================
    const int bsc = (lane & 3) ^ ((lane >> 3) & 3);
    const long bOffBase = (long)(b * 512 + wave * 64 + (lane >> 2)) * 256 + bsc * 8;
    const int bDstBase = (wave * 64) * 32;
    auto issueB = [&](int kt, int pb) {
        #pragma unroll
        for (int q = 0; q < 4; q++)
            gload_lds16(text_h + bOffBase + (long)q * 16 * 256 + kt * 32,
                        &BsL[pb * 16384 + bDstBase + q * 16 * 32]);
    };

    int abase[2], axm[2], bro[8];
    #pragma unroll
    for (int i = 0; i < 2; i++) {
        int r = wm + i * 16 + l16;
        abase[i] = r * 256; axm[i] = r & 7;
    }
    #pragma unroll
    for (int j = 0; j < 8; j++) {
        int n = wn + j * 16 + l16;
        bro[j] = n * 32 + ((quad ^ ((n >> 1) & 3)) << 3);
    }

    #pragma unroll
    for (int p = 0; p < 4; p++) {
        int row = p * 16 + (tid >> 5);
        int c   = tid & 31;
        int grow = m0 + row; if (grow > L - 1) grow = L - 1;
        gload_lds16(le_h + (long)grow * 256 + ((c ^ (row & 7)) << 3),
                    A_s + p * 4096 + wave * 512);
    }
    issueB(0, 0);
    issueB(1, 1);
    asm volatile("s_waitcnt vmcnt(4)" ::: "memory");   // A(4)+B0(4) landed
    asm volatile("s_barrier" ::: "memory");

    f32x4 acc[2][8] = {};
    #pragma unroll 1
    for (int t = 0; t < 8; t++) {
        const int pb = t & 1;
        f16x8 a[2], bf[8];
        #pragma unroll
        for (int i = 0; i < 2; i++)
            a[i] = *(const f16x8*)&A_s[abase[i] + (((t * 4 + quad) ^ axm[i]) << 3)];
        const unsigned short* bb = &BsL[pb * 16384];
        #pragma unroll
        for (int j = 0; j < 8; j++) bf[j] = *(const f16x8*)&bb[bro[j]];
        #pragma unroll
        for (int i = 0; i < 2; i++)
            #pragma unroll
            for (int j = 0; j < 8; j++)
                acc[i][j] = __builtin_amdgcn_mfma_f32_16x16x32_f16(
                    a[i], bf[j], acc[i][j], 0, 0, 0);
        if (t < 7) {
            asm volatile("s_waitcnt lgkmcnt(0)" ::: "memory");
            asm volatile("s_barrier" ::: "memory");
            int kt2 = (t + 2 <= 7) ? t + 2 : 7;
            issueB(kt2, pb);
            asm volatile("s_waitcnt vmcnt(4)" ::: "memory");
            asm volatile("s_barrier" ::: "memory");
        }
    }
    asm volatile("s_waitcnt vmcnt(0)" ::: "memory");   // drain dup DMA (mine)

    float mvv[8];
    #pragma unroll
    for (int j = 0; j < 8; j++) {
        int gs = wn + j * 16 + l16;
        int tok = tokens[(long)b * 512 + gs];
        mvv[j] = (tok == 0 || tok == 101 || tok == 102) ? 1e30f : 0.f;
    }
    #pragma unroll
    for (int i = 0; i < 2; i++)
        #pragma unroll
        for (int j = 0; j < 8; j++)
            #pragma unroll
            for (int r = 0; r < 4; r++) acc[i][j][r] -= mvv[j];

    const int wgrp = (wave >> 2) * 4;
    float M[2][4];
    #pragma unroll
    for (int i = 0; i < 2; i++)
        #pragma unroll
        for (int r = 0; r < 4; r++) {
            float v = acc[i][0][r];
            #pragma unroll
            for (int j = 1; j < 8; j++) v = fmaxf(v, acc[i][j][r]);
            #pragma unroll
            for (int d = 1; d <= 8; d <<= 1) v = fmaxf(v, __shfl_xor(v, d));
            if (l16 == 0) redm[wave][i * 16 + quad * 4 + r] = v;
        }
    __syncthreads();      // all waves past vmcnt(0) drain here -> LDS reusable
    #pragma unroll
    for (int i = 0; i < 2; i++)
        #pragma unroll
        for (int r = 0; r < 4; r++) {
            int rl = i * 16 + quad * 4 + r;
            float v = redm[wgrp][rl];
            #pragma unroll
            for (int k = 1; k < 4; k++) v = fmaxf(v, redm[wgrp + k][rl]);
            M[i][r] = v;
        }

    float psum[2][4] = {};
    #pragma unroll
    for (int i = 0; i < 2; i++)
        #pragma unroll
        for (int j = 0; j < 8; j++)
            #pragma unroll
            for (int r = 0; r < 4; r++) {
                float e = __expf(acc[i][j][r] - M[i][r]);
                acc[i][j][r] = e;
                psum[i][r] += e;
            }
    #pragma unroll
    for (int i = 0; i < 2; i++)
        #pragma unroll
        for (int r = 0; r < 4; r++) {
            float v = psum[i][r];
            #pragma unroll
            for (int d = 1; d <= 8; d <<= 1) v += __shfl_xor(v, d);
            if (l16 == 0) reds[wave][i * 16 + quad * 4 + r] = v;
        }
    __syncthreads();
    #pragma unroll
    for (int i = 0; i < 2; i++)
        #pragma unroll
        for (int r = 0; r < 4; r++) {
            int rl = i * 16 + quad * 4 + r;
            float s = reds[wgrp][rl] + reds[wgrp + 1][rl]
                    + reds[wgrp + 2][rl] + reds[wgrp + 3][rl];
            M[i][r] = 1.f / s;
        }

    // ---- write P to LDS (16B-chunk swizzle c ^= row&7); rows >= L zeroed ----
    #pragma unroll
    for (int i = 0; i < 2; i++)
        #pragma unroll
        for (int r = 0; r < 4; r++) {
            int ml = wm + i * 16 + quad * 4 + r;     // local row 0..63
            int gm = m0 + ml;
            #pragma unroll
            for (int j = 0; j < 8; j++) {
                int col = wn + j * 16 + l16;
                float pv = (gm < L) ? acc[i][j][r] * M[i][r] : 0.f;
                int c = col >> 3, w = col & 7;
                P[ml * 512 + ((c ^ (ml & 7)) << 3) + w] = f2h(pv);
            }
        }

    // ==================== Phase 2: PV (att_pv minus A-staging) ============
    const int wnp = (wave & 3) * 64;
    const long vOff0 = ((long)b * 256 + wave * 32 + (lane >> 2)) * 512 + bsc * 8;
    const long vOff1 = vOff0 + 16 * 512;
    const int vDst0 = (wave * 32) * 32, vDst1 = vDst0 + 16 * 32;
    auto issueV = [&](int kt, int pb) {
        gload_lds16(text_hT + vOff0 + kt * 32, Vb + pb * 8192 + vDst0);
        gload_lds16(text_hT + vOff1 + kt * 32, Vb + pb * 8192 + vDst1);
    };
    int paro[2], pxm[2], vro[4];
    #pragma unroll
    for (int i = 0; i < 2; i++) {
        int r = wm + i * 16 + l16;
        paro[i] = r * 512; pxm[i] = r & 7;
    }
    #pragma unroll
    for (int j = 0; j < 4; j++) {
        int n = wnp + j * 16 + l16;
        vro[j] = n * 32 + ((quad ^ ((n >> 1) & 3)) << 3);
    }

    issueV(0, 0);
    issueV(1, 1);
    asm volatile("s_waitcnt lgkmcnt(0)" ::: "memory");  // my P writes done
    asm volatile("s_waitcnt vmcnt(2)" ::: "memory");    // V(0) landed (own)
    asm volatile("s_barrier" ::: "memory");             // all P visible

    f32x4 accp[2][4] = {};
    #pragma unroll 1
    for (int t = 0; t < 16; t++) {
        const int pr = t % 3;
        f16x8 a2[2], vf[4];
        #pragma unroll
        for (int i = 0; i < 2; i++)
            a2[i] = *(const f16x8*)&P[paro[i] + (((t * 4 + quad) ^ pxm[i]) << 3)];
        const unsigned short* vb = Vb + pr * 8192;
        #pragma unroll
        for (int j = 0; j < 4; j++) vf[j] = *(const f16x8*)&vb[vro[j]];
        #pragma unroll
        for (int i = 0; i < 2; i++)
            #pragma unroll
            for (int j = 0; j < 4; j++)
                accp[i][j] = __builtin_amdgcn_mfma_f32_16x16x32_f16(
                    a2[i], vf[j], accp[i][j], 0, 0, 0);
        if (t < 15) {
            int kb = t + 2; if (kb > 15) kb = 15;       // tail: dup, dead buf
            issueV(kb, (t + 2) % 3);
            asm volatile("s_waitcnt vmcnt(2)" ::: "memory");
            asm volatile("s_barrier" ::: "memory");
        }
    }
    asm volatile("s_waitcnt vmcnt(0)" ::: "memory");

    // ---- epilogue: f16 store (verbatim att_pv) ----
    #pragma unroll
    for (int i = 0; i < 2; i++)
        #pragma unroll
        for (int j = 0; j < 4; j++)
            #pragma unroll
            for (int r = 0; r < 4; r++) {
                int gm = m0 + wm + i * 16 + quad * 4 + r;
                if (gm < L) {
                    int h = wnp + j * 16 + l16;
                    feat_h[(long)b * (L * H) + (long)gm * 256 + h] =
                        f2h(accp[i][j][r]);
                }
            }
}

// ---------------------------------------------------------------------------
// MFMA fp16 GEMM (EPI4 only). Tile = (32*IM) x 128, BK=32, 4 waves.
// ---------------------------------------------------------------------------
template<int EPI, bool CONVA, int IM>
__global__ __launch_bounds__(256) void gemm_mfma(
    const void* __restrict__ Aptr, int lda, long strA,
    const unsigned short* __restrict__ Bp, int ldb, long strB,
    float* __restrict__ C, int ldc, long strC,
    int M, int N, int K,
    const float* __restrict__ bias,
    const int* __restrict__ tokens,
    unsigned short* __restrict__ outH,
    unsigned short* __restrict__ outHT,
    int kChunk)
{
    __shared__ unsigned short A_s[32 * IM * 32];
    __shared__ unsigned short B_s[128 * 32];
    const int tid  = threadIdx.x;
    const int wave = tid >> 6, lane = tid & 63;
    const int quad = lane >> 4, l16 = lane & 15;
    const int bz = blockIdx.z;
    const int m0 = blockIdx.y * (32 * IM), n0 = blockIdx.x * 128;
    const int wm = (wave & 1) * (16 * IM), wn = (wave >> 1) * 64;

    long aBase, bBase;
    int kBeg, kEnd;
    if (EPI == 4) { aBase = 0; bBase = 0; kBeg = bz * kChunk; kEnd = kBeg + kChunk; }
    else { aBase = (long)bz * strA; bBase = (long)bz * strB; kBeg = 0; kEnd = K; }

    f32x4 acc[IM][4] = {};

    for (int k0 = kBeg; k0 < kEnd; k0 += 32) {
        if (CONVA) {
            const float* Af = (const float*)Aptr + aBase;
            #pragma unroll
            for (int it = 0; it < IM; it++) {
                int idx = it * 256 + tid;
                int row = idx >> 3, col4 = idx & 7;
                int gm = m0 + row; if (gm > M - 1) gm = M - 1;
                float4 v = *(const float4*)(Af + (long)gm * lda + k0 + col4 * 4);
                unsigned int p0 = f2h(v.x) | ((unsigned int)f2h(v.y) << 16);
                unsigned int p1 = f2h(v.z) | ((unsigned int)f2h(v.w) << 16);
                *(uint2*)&A_s[row * 32 + col4 * 4] = make_uint2(p0, p1);
            }
        } else {
            const unsigned short* Ab = (const unsigned short*)Aptr + aBase;
            #pragma unroll
            for (int t = 0; t < IM / 2; t++) {
                int rowb = wave * (8 * IM) + t * 16;
                int gm = m0 + rowb + (lane >> 2); if (gm > M - 1) gm = M - 1;
                gload_lds16(Ab + (long)gm * lda + k0 + (lane & 3) * 8,
                            &A_s[rowb * 32]);
            }
        }
        #pragma unroll
        for (int t = 0; t < 2; t++) {
            int rowb = wave * 32 + t * 16;
            int gn = n0 + rowb + (lane >> 2); if (gn > N - 1) gn = N - 1;
            gload_lds16(Bp + bBase + (long)gn * ldb + k0 + (lane & 3) * 8,
                        &B_s[rowb * 32]);
        }
        __syncthreads();
        f16x8 a[IM], b[4];
        #pragma unroll
        for (int i = 0; i < IM; i++)
            a[i] = *(const f16x8*)&A_s[(wm + i * 16 + l16) * 32 + quad * 8];
        #pragma unroll
        for (int j = 0; j < 4; j++)
            b[j] = *(const f16x8*)&B_s[(wn + j * 16 + l16) * 32 + quad * 8];
        #pragma unroll
        for (int i = 0; i < IM; i++)
            #pragma unroll
            for (int j = 0; j < 4; j++)
                acc[i][j] = __builtin_amdgcn_mfma_f32_16x16x32_f16(
                    a[i], b[j], acc[i][j], 0, 0, 0);
        __syncthreads();
    }

    #pragma unroll
    for (int i = 0; i < IM; i++) {
        #pragma unroll
        for (int j = 0; j < 4; j++) {
            #pragma unroll
            for (int r = 0; r < 4; r++) {
                int ml = wm + i * 16 + quad * 4 + r;
                int nl = wn + j * 16 + l16;
                int gm = m0 + ml, gn = n0 + nl;
                if (gm >= M || gn >= N) continue;
                float v = acc[i][j][r];
                if (EPI == 2) {
                    int tok = tokens[(long)bz * 512 + gn];
                    if (tok == 0 || tok == 101 || tok == 102) v -= 1e30f;
                    C[(long)bz * strC + (long)gm * ldc + gn] = v;
                } else if (EPI == 3) {
                    outH[(long)bz * strC + (long)gm * ldc + gn] = f2h(v);
                } else { // EPI 4: partial K-slice
                    C[(long)bz * strC + (long)gm * ldc + gn] = v;
                }
            }
        }
    }
}

// out = sigmoid(bias + sum of nz partial K-slices)
__global__ __launch_bounds__(256) void out_final(
    const float* __restrict__ acc, const float* __restrict__ ob,
    float* __restrict__ out, int total, int nz)
{
    int i = blockIdx.x * 256 + threadIdx.x;
    if (i >= total) return;
    float v = ob[i % L];
    #pragma unroll 4
    for (int z = 0; z < nz; z++) v += acc[(long)z * total + i];
    out[i] = sigf(v);
}

extern "C" void kernel_launch(void* const* d_in, const int* in_sizes, int n_in,
                              void* d_out, int out_size, void* d_ws, size_t ws_size,
                              hipStream_t stream)
{
    (void)in_sizes; (void)n_in; (void)out_size; (void)ws_size;
    const int*   inputs      = (const int*)d_in[0];
    const float* text_hidden = (const float*)d_in[1];
    const float* label_enc   = (const float*)d_in[2];
    const float* w12   = (const float*)d_in[3];
    const float* w23   = (const float*)d_in[4];
    const float* fre12 = (const float*)d_in[5];
    const float* fre23 = (const float*)d_in[6];
    const float* wi1_W = (const float*)d_in[7],  *wi1_b = (const float*)d_in[8];
    const float* wf1_W = (const float*)d_in[9],  *wf1_b = (const float*)d_in[10];
    const float* wo1_W = (const float*)d_in[11], *wo1_b = (const float*)d_in[12];
    const float* wu1_W = (const float*)d_in[13], *wu1_b = (const float*)d_in[14];
    const float* wi2_W = (const float*)d_in[15], *wi2_b = (const float*)d_in[16];
    const float* wf2_W = (const float*)d_in[17], *wf2_b = (const float*)d_in[18];
    const float* wo2_W = (const float*)d_in[19], *wo2_b = (const float*)d_in[20];
    const float* wu2_W = (const float*)d_in[21], *wu2_b = (const float*)d_in[22];
    const float* ui1_W = (const float*)d_in[23], *uf1_W = (const float*)d_in[24];
    const float* uo1_W = (const float*)d_in[25], *uu1_W = (const float*)d_in[26];
    const float* ui2_W = (const float*)d_in[27], *uf2_W = (const float*)d_in[28];
    const float* uo2_W = (const float*)d_in[29], *uu2_W = (const float*)d_in[30];
    const float* mix_W = (const float*)d_in[31], *mix_b = (const float*)d_in[32];
    const float* tt_W  = (const float*)d_in[33], *tt_b  = (const float*)d_in[34];
    const float* Amat  = (const float*)d_in[35], *Wp    = (const float*)d_in[36];
    const float* out_W = (const float*)d_in[37], *out_b = (const float*)d_in[38];
    float* out = (float*)d_out;

    // ---- workspace (float units, 16B-aligned chunks) ----
    float* ws = (float*)d_ws;
    float* att     = ws; ws += (long)B * L * S;                                 // (unused, layout kept)
    unsigned short* text_h  = (unsigned short*)ws; ws += (long)B * S * H / 2;   // [b*s][h]
    unsigned short* text_hT = (unsigned short*)ws; ws += (long)B * S * H / 2;   // [b][h][s]
    unsigned short* att_h   = (unsigned short*)ws; ws += (long)B * L * S / 2;   // (unused)
    unsigned short* tt_Wt   = (unsigned short*)ws; ws += 768 * H / 2;           // tiled [24][256][32]
    unsigned short* le_h    = (unsigned short*)ws; ws += L * H / 2 + 4;
    unsigned short* out_Wh  = (unsigned short*)ws; ws += (long)L * 36096 / 2;   // [n][k]
    unsigned short* feat_h  = (unsigned short*)ws; ws += (long)B * L * H / 2;   // [b][l*256+h]
    float* outacc = ws; ws += (long)B * L * 141;                                // partial K-slices
    float* G    = ws; ws += 7 * 141 * 256;
    float* tmpP = ws; ws += L * H;
    float* wv2f = ws; ws += N3 * H;
    float* wv1f = ws; ws += N2 * H;
    float* h11  = ws; ws += N1 * H;  float* c11  = ws; ws += N1 * H;
    float* h21  = ws; ws += N2 * H;  float* c21  = ws; ws += N2 * H;
    float* h21t = ws; ws += N2 * H;  float* c21p = ws; ws += N2 * H;
    float* h31  = ws; ws += N3 * H;  float* h31t = ws; ws += N3 * H;
    float* c31p = ws; ws += N3 * H;
    float* h32  = ws; ws += N3 * H;  float* c32  = ws; ws += N3 * H;
    float* h22  = ws; ws += N2 * H;  float* c22  = ws; ws += N2 * H;
    float* h22t = ws; ws += N2 * H;  float* fcb  = ws; ws += N3 * H;
    float* h12  = ws; ws += N1 * H;  float* h12t = ws; ws += N1 * H;
    float* fc2b = ws; ws += N2 * H;
    (void)att; (void)att_h;

    // 1. prep (tt_W tile + out_W transpose) + gate pre-activations + pre2
    prep_gates<<<24 + 1692 + 3948 + 1092, 256, 0, stream>>>(
        tt_W, tt_Wt, out_W, out_Wh, label_enc,
        wi1_W, wf1_W, wo1_W, wu1_W, wi2_W, wo2_W, wu2_W,
        wi1_b, wf1_b, wo1_b, wu1_b, wi2_b, wo2_b, wu2_b,
        Amat, w23, w12, Wp, wf2_W, G, tmpP, wv2f, wv1f);
    // 2. text = tanh(text_hidden @ tt_W + b) -> fp16 both layouts (pipelined)
    text_gemm3<<<512, 512, 0, stream>>>(
        text_hidden, tt_Wt, tt_b, text_h, text_hT);
    // 3-7. label chain
    ew1<<<107, 256, 0, stream>>>(G, h11, c11, h32, c32);
    chain_mm<<<dim3(4, 200), 256, 0, stream>>>(0, w12, w23, fre23, fre12,
        h11, c11, h32, h21, c21, h22, wv2f, wv1f, wf2_b, uf2_W, c32, c22,
        h21t, c21p, h22t, fcb, h31t, c31p, h12t, fc2b);
    lstm_fused<<<dim3(4, 68), 256, 0, stream>>>(0, G,
        h21t, c21p, h22t, fcb, h31t, c31p, h12t, fc2b, w23, w12,
        ui1_W, uf1_W, uo1_W, uu1_W, ui2_W, uo2_W, uu2_W,
        h21, c21, h22, c22, h31, h12);
    chain_mm<<<dim3(4, 239), 256, 0, stream>>>(1, w12, w23, fre23, fre12,
        h11, c11, h32, h21, c21, h22, wv2f, wv1f, wf2_b, uf2_W, c32, c22,
        h21t, c21p, h22t, fcb, h31t, c31p, h12t, fc2b);
    lstm_fused<<<dim3(4, 107), 256, 0, stream>>>(1, G,
        h21t, c21p, h22t, fcb, h31t, c31p, h12t, fc2b, w23, w12,
        ui1_W, uf1_W, uo1_W, uu1_W, ui2_W, uo2_W, uu2_W,
        h21, c21, h22, c22, h31, h12);
    mix_mm<<<dim3(4, 141), 256, 0, stream>>>(h11, h12, h21, h22, h31, h32,
        tmpP, mix_W, mix_b, le_h);
    // 8. logits + mask + softmax + PV fused -> feat_h
    att_fused<<<dim3(3, 64), 512, 0, stream>>>(
        le_h, text_h, text_hT, inputs, feat_h);
    // 9. out-head: K-split MFMA -> 141 partial slices (no atomics)
    gemm_mfma<4, false, 2><<<dim3(2, 1, 141), 256, 0, stream>>>(
        feat_h, L * H, 0, out_Wh, L * H, 0, outacc, L, (long)B * L,
        B, L, L * H, nullptr, nullptr, nullptr, nullptr, 256);
    // 10. reduce + sigmoid + bias
    out_final<<<(B * L + 255) / 256, 256, 0, stream>>>(outacc, out_b, out, B * L, 141);
}

// Round 11
// 423.755 us; speedup vs baseline: 1.0456x; 1.0064x over previous
//
#include <hip/hip_runtime.h>
#include <math.h>

// Problem constants
static constexpr int H = 256, L = 141, N1 = 9, N2 = 34, N3 = 98;
static constexpr int B = 64, S = 512;

typedef __attribute__((ext_vector_type(8))) _Float16 f16x8;
typedef __attribute__((ext_vector_type(4))) float f32x4;

__device__ inline unsigned short f2h(float x) {
    _Float16 h = (_Float16)x;
    return __builtin_bit_cast(unsigned short, h);
}
__device__ inline float sigf(float x) { return 1.f / (1.f + __expf(-x)); }

__device__ inline void gload_lds16(const void* g, void* l) {
    __builtin_amdgcn_global_load_lds(
        (const __attribute__((address_space(1))) void*)g,
        (__attribute__((address_space(3))) void*)l, 16, 0, 0);
}

// ---------------------------------------------------------------------------
// prep_gates: prep (conv_ttW 24 + out_W transpose 1692) + gate_pre/ew1
// restructured + pre2.  Gate restructure (round 11): G-rows used ONLY by
// ew1 are computed locally (3 sequential verbatim gate reductions) and the
// ew1 elementwise applied in-block -> ew1 launch eliminated. Partition:
//  keep (write G): j in 4..6 rows 0..8 | all j rows 9..42 | j 0..3 rows 43..140
//  ew1a (h11,c11): gates {0,2,3} rows 0..8   (36 blocks)
//  ew1b (h32,c32): gates {4,5,6} rows 43..140 (392 blocks)
//  dead: j=1 rows 0..8 (never read) -> skipped.
// All gate values = red-sum + bias, bitwise identical to G-then-read path.
// ---------------------------------------------------------------------------
__global__ __launch_bounds__(256) void prep_gates(
    const float* __restrict__ ttW, unsigned short* __restrict__ Bt,
    const float* __restrict__ outW, unsigned short* __restrict__ outWh,
    const float* __restrict__ le,
    const float* W0, const float* W1, const float* W2, const float* W3,
    const float* W4, const float* W5, const float* W6,
    const float* b0, const float* b1, const float* b2, const float* b3,
    const float* b4, const float* b5, const float* b6,
    const float* __restrict__ Amat, const float* __restrict__ w23,
    const float* __restrict__ w12, const float* __restrict__ Wp,
    const float* __restrict__ wf2_W,
    float* __restrict__ G, float* __restrict__ tmpP,
    float* __restrict__ wv2f, float* __restrict__ wv1f,
    float* __restrict__ h11, float* __restrict__ c11,
    float* __restrict__ h32, float* __restrict__ c32)
{
    __shared__ float sf[4112];                   // union: 16448 B
    unsigned short* su = (unsigned short*)sf;
    const int tid = threadIdx.x;
    const int bx = blockIdx.x;
    const int nl = tid & 63, ks = tid >> 6;
    if (bx < 24) {
        // ---- conv_ttW body ----
        const int t = bx;
        #pragma unroll
        for (int p = 0; p < 32; p++) {
            int lin = p * 256 + tid;
            int r = lin >> 8, c = lin & 255;
            su[r * 257 + c] = f2h(ttW[(long)(t * 32 + r) * 256 + c]);
        }
        __syncthreads();
        unsigned short v[32];
        #pragma unroll
        for (int kin = 0; kin < 32; kin++) v[kin] = su[kin * 257 + tid];
        uint4* dst = (uint4*)(Bt + ((long)t * 256 + tid) * 32);
        #pragma unroll
        for (int q = 0; q < 4; q++) dst[q] = ((const uint4*)v)[q];
    } else if (bx < 24 + 1692) {
        // ---- transp_t64 body for out_W (R=36096, C=141) ----
        const int u = bx - 24;
        const int r0 = (u % 564) * 64, c0 = (u / 564) * 64;
        const int R = 36096, C = 141;
        #pragma unroll
        for (int p = 0; p < 16; p++) {
            int lin = p * 256 + tid;
            int r = lin >> 6, c = lin & 63;
            int gc = c0 + c;
            float v = (gc < C) ? outW[(long)(r0 + r) * C + gc] : 0.f;
            su[c * 65 + r] = f2h(v);
        }
        __syncthreads();
        #pragma unroll
        for (int p = 0; p < 16; p++) {
            int lin = p * 256 + tid;
            int c = lin >> 6, r = lin & 63;
            if (c0 + c < C)
                outWh[(long)(c0 + c) * R + r0 + r] = su[c * 65 + r];
        }
    } else if (bx < 24 + 1692 + 3056) {
        // ---- gates section ----
        const int u = bx - (24 + 1692);
        float* ls = sf; float* red = sf + 256;
        if (u < 2628) {
            // keep blocks: write G (verbatim gate_pre body, remapped j,m)
            int j, m, x;
            if (u < 108)       { x = u & 3; int v = u >> 2; m = v / 3;      j = 4 + v % 3; }
            else if (u < 1060) { int w = u - 108;  x = w & 3; int v = w >> 2; m = 9 + v / 7;  j = v % 7; }
            else               { int w = u - 1060; x = w & 3; int v = w >> 2; m = 43 + v / 4; j = v % 4; }
            const int n = x * 64 + nl;
            ls[tid] = le[(long)m * 256 + tid];
            __syncthreads();
            const float *W, *bb2;
            switch (j) {
                case 0: W = W0; bb2 = b0; break;  case 1: W = W1; bb2 = b1; break;
                case 2: W = W2; bb2 = b2; break;  case 3: W = W3; bb2 = b3; break;
                case 4: W = W4; bb2 = b4; break;  case 5: W = W5; bb2 = b5; break;
                default: W = W6; bb2 = b6;
            }
            float a0 = 0, a1 = 0, a2 = 0, a3 = 0;
            for (int k = ks; k + 12 < 256; k += 16) {
                long o = (long)k * 256 + n;
                a0 += ls[k] * W[o];        a1 += ls[k + 4] * W[o + 1024];
                a2 += ls[k + 8] * W[o + 2048]; a3 += ls[k + 12] * W[o + 3072];
            }
            red[tid] = a0 + a1 + a2 + a3;
            __syncthreads();
            if (ks == 0)
                G[((long)j * 141 + m) * 256 + n] =
                    red[nl] + red[64 + nl] + red[128 + nl] + red[192 + nl] + bb2[n];
        } else {
            // ew1a (36) / ew1b (392): 3 local gate reductions + elementwise
            const bool ea = (u < 2628 + 36);
            const int w = ea ? (u - 2628) : (u - 2664);
            const int x = w & 3, idx = w >> 2;          // ea: m 0..8; eb: r 0..97
            const int m = ea ? idx : 43 + idx;
            const int n = x * 64 + nl;
            const float* Wg[3]; const float* bg[3];
            if (ea) { Wg[0] = W0; Wg[1] = W2; Wg[2] = W3;
                      bg[0] = b0; bg[1] = b2; bg[2] = b3; }
            else    { Wg[0] = W4; Wg[1] = W5; Wg[2] = W6;
                      bg[0] = b4; bg[1] = b5; bg[2] = b6; }
            ls[tid] = le[(long)m * 256 + tid];
            __syncthreads();
            float gv[3] = {0.f, 0.f, 0.f};
            #pragma unroll
            for (int g = 0; g < 3; g++) {
                const float* W = Wg[g];
                float a0 = 0, a1 = 0, a2 = 0, a3 = 0;
                for (int k = ks; k + 12 < 256; k += 16) {
                    long o = (long)k * 256 + n;
                    a0 += ls[k] * W[o];        a1 += ls[k + 4] * W[o + 1024];
                    a2 += ls[k + 8] * W[o + 2048]; a3 += ls[k + 12] * W[o + 3072];
                }
                red[tid] = a0 + a1 + a2 + a3;
                __syncthreads();
                if (ks == 0)
                    gv[g] = red[nl] + red[64 + nl] + red[128 + nl] + red[192 + nl]
                          + bg[g][n];
                __syncthreads();
            }
            if (ks == 0) {
                float iv = sigf(gv[0]);
                float ov = sigf(gv[1]);
                float uv = tanhf(gv[2]);
                float cv = iv * uv;
                if (ea) { c11[idx * 256 + n] = cv; h11[idx * 256 + n] = ov * tanhf(cv); }
                else    { c32[idx * 256 + n] = cv; h32[idx * 256 + n] = ov * tanhf(cv); }
            }
        }
    } else {
        // ---- pre2 body ----
        const int u = bx - (24 + 1692 + 3056);
        const int x = u % 4, y = u / 4, n = x * 64 + nl;
        int job, m, K1;
        if (y < 141)      { job = 0; m = y;       K1 = 141; }
        else if (y < 239) { job = 1; m = y - 141; K1 = 34; }
        else              { job = 2; m = y - 239; K1 = 9; }
        float* cs = sf; float* t = sf + 256; float* red = sf + 512;
        if (tid < K1)
            cs[tid] = (job == 0) ? Amat[(long)m * 141 + tid]
                    : (job == 1) ? w23[(long)tid * 98 + m]
                                 : w12[(long)tid * 34 + m];
        __syncthreads();
        const float* s1 = (job == 1) ? le + 9 * 256 : le;
        float acc = 0;
        #pragma unroll 4
        for (int k = 0; k < K1; k++) acc += cs[k] * s1[(long)k * 256 + tid];
        t[tid] = acc;
        __syncthreads();
        const float* W = (job == 0) ? Wp : wf2_W;
        float a0 = 0, a1 = 0, a2 = 0, a3 = 0;
        for (int k = ks; k + 12 < 256; k += 16) {
            long o = (long)k * 256 + n;
            a0 += t[k] * W[o];        a1 += t[k + 4] * W[o + 1024];
            a2 += t[k + 8] * W[o + 2048]; a3 += t[k + 12] * W[o + 3072];
        }
        red[tid] = a0 + a1 + a2 + a3;
        __syncthreads();
        if (ks == 0) {
            float tot = red[nl] + red[64 + nl] + red[128 + nl] + red[192 + nl];
            if (job == 0)      tmpP[(long)m * 256 + n] = fmaxf(tot, 0.f);
            else if (job == 1) wv2f[(long)m * 256 + n] = tot;
            else               wv1f[(long)m * 256 + n] = tot;
        }
    }
}

// ---------------------------------------------------------------------------
// text_gemm3: pipelined LDS-staged GEMM (round-3/8, proven best). Unchanged.
// ---------------------------------------------------------------------------
__global__ __launch_bounds__(512, 4) void text_gemm3(
    const float* __restrict__ Af,            // [32768][768] fp32
    const unsigned short* __restrict__ Bt,   // [24][256][32] f16 tiled
    const float* __restrict__ bias,          // [256]
    unsigned short* __restrict__ outH,       // [32768][256] fp16
    unsigned short* __restrict__ outHT)      // [64][256][512] fp16
{
    __shared__ unsigned short smem[28672];   // 57344 B
    unsigned short* As = smem;               // 2 x [64][32]  (4096 shorts)
    unsigned short* Bs = smem + 4096;        // 3 x [256][32] (24576 shorts)
    unsigned short* T  = smem;               // epilogue alias: [256][72]

    const int tid  = threadIdx.x;
    const int wave = tid >> 6, lane = tid & 63;
    const int quad = lane >> 4, l16 = lane & 15;
    const int m0 = blockIdx.x * 64;
    const int wm = (wave >> 2) * 32;         // 2 m-groups
    const int wn = (wave & 3) * 64;          // 4 n-groups

    const int arow = tid >> 3;               // 0..63
    const int ac16 = tid & 7;                // 0..7 (16B fp32 chunks)
    const float* aSrc = Af + (long)(m0 + arow) * 768 + ac16 * 4;
    const int ac8d = ac16 ^ ((arow & 3) << 1);
    const int aWoff = arow * 32 + ac8d * 4;  // shorts

    const int bsc = (lane & 3) ^ ((lane >> 3) & 3);     // src chunk16 swizzle
    const long bSrcOff0 = (long)(wave * 32 + (lane >> 2)) * 32 + bsc * 8;
    const long bSrcOff1 = bSrcOff0 + 16 * 32;
    const int bDst0 = (wave * 32) * 32, bDst1 = (wave * 32 + 16) * 32;

    int aro[2], bro[4];
    #pragma unroll
    for (int i = 0; i < 2; i++) {
        int r = wm + i * 16 + l16;
        aro[i] = r * 32 + ((quad * 2) ^ ((r & 3) << 1)) * 4;
    }
    #pragma unroll
    for (int j = 0; j < 4; j++) {
        int n = wn + j * 16 + l16;
        bro[j] = n * 32 + ((quad ^ ((n >> 1) & 3)) << 3);
    }

    f32x4 acc[2][4] = {};
    float4 ar0, ar1;

    auto issueB = [&](int kt, int pb) {
        const unsigned short* src = Bt + (long)kt * 8192;
        unsigned short* d = Bs + pb * 8192;
        gload_lds16(src + bSrcOff0, d + bDst0);
        gload_lds16(src + bSrcOff1, d + bDst1);
    };
    auto writeA = [&](const float4& v, int pa) {
        unsigned int p0 = f2h(v.x) | ((unsigned int)f2h(v.y) << 16);
        unsigned int p1 = f2h(v.z) | ((unsigned int)f2h(v.w) << 16);
        *(uint2*)&As[pa * 2048 + aWoff] = make_uint2(p0, p1);
    };

    ar0 = *(const float4*)(aSrc + 0 * 32);
    issueB(0, 0);
    ar1 = *(const float4*)(aSrc + 1 * 32);
    issueB(1, 1);
    asm volatile("s_waitcnt vmcnt(5)" ::: "memory");   // A(0) landed
    writeA(ar0, 0);
    asm volatile("s_waitcnt vmcnt(3)" ::: "memory");   // B(0) landed (own)
    asm volatile("s_waitcnt lgkmcnt(0)" ::: "memory");
    asm volatile("s_barrier" ::: "memory");

    auto body = [&](int t, float4& arIn, float4& arOut, int pa, int pr) {
        int kt2 = (t + 2 <= 23) ? t + 2 : 23;
        arOut = *(const float4*)(aSrc + kt2 * 32);
        f16x8 a[2], b[4];
        const unsigned short* ab = As + pa * 2048;
        const unsigned short* bb = Bs + pr * 8192;
        #pragma unroll
        for (int i = 0; i < 2; i++) a[i] = *(const f16x8*)&ab[aro[i]];
        #pragma unroll
        for (int j = 0; j < 4; j++) b[j] = *(const f16x8*)&bb[bro[j]];
        #pragma unroll
        for (int i = 0; i < 2; i++)
            #pragma unroll
            for (int j = 0; j < 4; j++)
                acc[i][j] = __builtin_amdgcn_mfma_f32_16x16x32_f16(
                    a[i], b[j], acc[i][j], 0, 0, 0);
        asm volatile("s_waitcnt vmcnt(3)" ::: "memory");
        writeA(arIn, pa ^ 1);
        int pw = pr + 2; if (pw >= 3) pw -= 3;
        issueB(kt2, pw);
        asm volatile("s_waitcnt vmcnt(3)" ::: "memory");
        asm volatile("s_waitcnt lgkmcnt(0)" ::: "memory");
        asm volatile("s_barrier" ::: "memory");
    };

    int pr = 0;
    #pragma unroll 1
    for (int t = 0; t < 24; t += 2) {
        body(t,     ar1, ar0, 0, pr);
        int pr1 = pr + 1; if (pr1 >= 3) pr1 -= 3;
        body(t + 1, ar0, ar1, 1, pr1);
        pr = pr1 + 1; if (pr >= 3) pr -= 3;
    }
    asm volatile("s_waitcnt vmcnt(0)" ::: "memory");
    __syncthreads();

    float bv[4];
    #pragma unroll
    for (int j = 0; j < 4; j++) bv[j] = bias[wn + j * 16 + l16];

    #pragma unroll
    for (int i = 0; i < 2; i++) {
        #pragma unroll
        for (int j = 0; j < 4; j++) {
            const int mlb = wm + i * 16 + quad * 4;
            const int n   = wn + j * 16 + l16;
            unsigned short hv[4];
            #pragma unroll
            for (int r = 0; r < 4; r++) {
                float v = tanhf(acc[i][j][r] + bv[j]);
                hv[r] = f2h(v);
                outH[(long)(m0 + mlb + r) * 256 + n] = hv[r];
            }
            uint2 p;
            p.x = hv[0] | ((unsigned int)hv[1] << 16);
            p.y = hv[2] | ((unsigned int)hv[3] << 16);
            *(uint2*)&T[n * 72 + mlb] = p;
        }
    }
    __syncthreads();
    {
        const int bb2 = m0 >> 9, s0 = m0 & 511;
        const int n = tid >> 1, half = tid & 1;
        const uint4* src = (const uint4*)&T[n * 72 + half * 32];
        uint4* dst = (uint4*)&outHT[((long)bb2 * 256 + n) * 512 + s0 + half * 32];
        dst[0] = src[0]; dst[1] = src[1];
        dst[2] = src[2]; dst[3] = src[3];
    }
}

// chain_mm: fused sparse/row matmuls.
__global__ __launch_bounds__(256) void chain_mm(int phase,
    const float* __restrict__ w12, const float* __restrict__ w23,
    const float* __restrict__ fre23, const float* __restrict__ fre12,
    const float* __restrict__ h11, const float* __restrict__ c11,
    const float* __restrict__ h32,
    const float* __restrict__ h21, const float* __restrict__ c21,
    const float* __restrict__ h22,
    const float* __restrict__ wv2f, const float* __restrict__ wv1f,
    const float* __restrict__ wf2_b, const float* __restrict__ uf2_W,
    const float* __restrict__ c32, const float* __restrict__ c22,
    float* __restrict__ h21t, float* __restrict__ c21p,
    float* __restrict__ h22t, float* __restrict__ fcb,
    float* __restrict__ h31t, float* __restrict__ c31p,
    float* __restrict__ h12t, float* __restrict__ fc2b)
{
    __shared__ float cs[256];
    __shared__ float red[256];
    const int x = blockIdx.x, y = blockIdx.y;
    const int tid = threadIdx.x, nl = tid & 63, ks = tid >> 6, n = x * 64 + nl;
    int job, m;
    if (phase == 0) {
        if (y < 34)       { job = 0; m = y; }
        else if (y < 68)  { job = 1; m = y - 34; }
        else if (y < 102) { job = 2; m = y - 68; }
        else              { job = 3; m = y - 102; }
    } else {
        if (y < 98)       { job = 0; m = y; }
        else if (y < 196) { job = 1; m = y - 98; }
        else if (y < 205) { job = 2; m = y - 196; }
        else              { job = 3; m = y - 205; }
    }
    if (job < 3) {
        int K; const float* src; float* dst;
        if (phase == 0) {
            K = (job == 2) ? 98 : 9;
            src = (job == 0) ? h11 : (job == 1) ? c11 : h32;
            dst = (job == 0) ? h21t : (job == 1) ? c21p : h22t;
            if (tid < K)
                cs[tid] = (job == 2) ? fre23[(long)m * 98 + tid]
                                     : w12[(long)tid * 34 + m];
        } else {
            K = 34;
            src = (job == 0) ? h21 : (job == 1) ? c21 : h22;
            dst = (job == 0) ? h31t : (job == 1) ? c31p : h12t;
            if (tid < K)
                cs[tid] = (job == 2) ? fre12[(long)m * 34 + tid]
                                     : w23[(long)tid * 98 + m];
        }
        __syncthreads();
        float a0 = 0;
        for (int k = ks; k < K; k += 4) a0 += cs[k] * src[(long)k * 256 + n];
        red[tid] = a0;
        __syncthreads();
        if (ks == 0)
            dst[(long)m * 256 + n] = red[nl] + red[64 + nl] + red[128 + nl] + red[192 + nl];
    } else {
        const float* row = (phase == 0) ? h32 + m * 256 : h22 + m * 256;
        const float* pre = (phase == 0) ? wv2f : wv1f;
        const float* cm  = (phase == 0) ? c32 : c22;
        float* dst       = (phase == 0) ? fcb : fc2b;
        cs[tid] = row[tid];
        __syncthreads();
        float a0 = 0, a1 = 0, a2 = 0, a3 = 0;
        for (int k = ks; k + 12 < 256; k += 16) {
            long o = (long)k * 256 + n;
            a0 += cs[k] * uf2_W[o];        a1 += cs[k + 4] * uf2_W[o + 1024];
            a2 += cs[k + 8] * uf2_W[o + 2048]; a3 += cs[k + 12] * uf2_W[o + 3072];
        }
        red[tid] = a0 + a1 + a2 + a3;
        __syncthreads();
        if (ks == 0) {
            float tot = red[nl] + red[64 + nl] + red[128 + nl] + red[192 + nl]
                      + pre[(long)m * 256 + n] + wf2_b[n];
            dst[(long)m * 256 + n] = sigf(tot) * cm[(long)m * 256 + n];
        }
    }
}

// lstm_fused: fused gate matmuls + elementwise.
__global__ __launch_bounds__(256) void lstm_fused(int phase,
    const float* __restrict__ G,
    const float* __restrict__ h21t, const float* __restrict__ c21p,
    const float* __restrict__ h22t, const float* __restrict__ fcb,
    const float* __restrict__ h31t, const float* __restrict__ c31p,
    const float* __restrict__ h12t, const float* __restrict__ fc2b,
    const float* __restrict__ w23, const float* __restrict__ w12,
    const float* __restrict__ ui1, const float* __restrict__ uf1,
    const float* __restrict__ uo1, const float* __restrict__ uu1,
    const float* __restrict__ ui2, const float* __restrict__ uo2,
    const float* __restrict__ uu2,
    float* __restrict__ h21, float* __restrict__ c21,
    float* __restrict__ h22, float* __restrict__ c22,
    float* __restrict__ h31, float* __restrict__ h12)
{
    __shared__ float hs[256];
    __shared__ float cs[128];
    __shared__ float red[1024];
    const int x = blockIdx.x, y = blockIdx.y;
    const int tid = threadIdx.x, nl = tid & 63, ks = tid >> 6, n = x * 64 + nl;
    bool modef; int m, grow, Kx = 0;
    const float *hrow, *U0, *U1, *U2, *U3 = nullptr, *Sx = nullptr, *cmod = nullptr;
    float *ho, *co = nullptr;
    if (phase == 0) {
        if (y < 34) { modef = true;  m = y;      grow = 9 + m;  hrow = h21t;
                      U0 = ui1; U1 = uf1; U2 = uo1; U3 = uu1; cmod = c21p; ho = h21; co = c21; }
        else        { modef = false; m = y - 34; grow = 9 + m;  hrow = h22t;
                      U0 = ui2; U1 = uo2; U2 = uu2; Sx = fcb; Kx = 98; ho = h22; co = c22;
                      if (tid < 98) cs[tid] = w23[(long)m * 98 + tid]; }
    } else {
        if (y < 98) { modef = true;  m = y;      grow = 43 + m; hrow = h31t;
                      U0 = ui1; U1 = uf1; U2 = uo1; U3 = uu1; cmod = c31p; ho = h31; co = nullptr; }
        else        { modef = false; m = y - 98; grow = m;      hrow = h12t;
                      U0 = ui2; U1 = uo2; U2 = uu2; Sx = fc2b; Kx = 34; ho = h12; co = nullptr;
                      if (tid < 34) cs[tid] = w12[(long)m * 34 + tid]; }
    }
    hs[tid] = hrow[(long)m * 256 + tid];
    __syncthreads();
    float a0 = 0, a1 = 0, a2 = 0, a3 = 0;
    if (modef) {
        for (int k = ks; k < 256; k += 4) {
            float xv = hs[k]; long o = (long)k * 256 + n;
            a0 += xv * U0[o]; a1 += xv * U1[o]; a2 += xv * U2[o]; a3 += xv * U3[o];
        }
    } else {
        for (int k = ks; k < 256; k += 4) {
            float xv = hs[k]; long o = (long)k * 256 + n;
            a0 += xv * U0[o]; a1 += xv * U1[o]; a2 += xv * U2[o];
        }
        for (int k = ks; k < Kx; k += 4) a3 += cs[k] * Sx[(long)k * 256 + n];
    }
    red[tid] = a0; red[256 + tid] = a1; red[512 + tid] = a2; red[768 + tid] = a3;
    __syncthreads();
    if (ks == 0) {
        float t0 = 0, t1 = 0, t2 = 0, t3 = 0;
        #pragma unroll
        for (int s2 = 0; s2 < 4; s2++) {
            t0 += red[s2 * 64 + nl];       t1 += red[256 + s2 * 64 + nl];
            t2 += red[512 + s2 * 64 + nl]; t3 += red[768 + s2 * 64 + nl];
        }
        if (modef) {
            float ti = t0 + G[(0L * 141 + grow) * 256 + n];
            float tf = t1 + G[(1L * 141 + grow) * 256 + n];
            float to = t2 + G[(2L * 141 + grow) * 256 + n];
            float tu = t3 + G[(3L * 141 + grow) * 256 + n];
            float cv = sigf(ti) * tanhf(tu) + sigf(tf) * cmod[(long)m * 256 + n];
            ho[(long)m * 256 + n] = sigf(to) * tanhf(cv);
            if (co) co[(long)m * 256 + n] = cv;
        } else {
            float ti = t0 + G[(4L * 141 + grow) * 256 + n];
            float to = t1 + G[(5L * 141 + grow) * 256 + n];
            float tu = t2 + G[(6L * 141 + grow) * 256 + n];
            float cv = sigf(ti) * tanhf(tu) + t3;
            ho[(long)m * 256 + n] = sigf(to) * tanhf(cv);
            if (co) co[(long)m * 256 + n] = cv;
        }
    }
}

// le_h[l] = fp16( [h?1(l) | h?2(l) | tmpP(l)] @ mix_W + mix_b ). grid (4,141)
__global__ __launch_bounds__(256) void mix_mm(
    const float* __restrict__ h11, const float* __restrict__ h12,
    const float* __restrict__ h21, const float* __restrict__ h22,
    const float* __restrict__ h31, const float* __restrict__ h32,
    const float* __restrict__ tmpP, const float* __restrict__ mix_W,
    const float* __restrict__ mix_b, unsigned short* __restrict__ le_h)
{
    __shared__ float ls[768];
    __shared__ float red[256];
    const int x = blockIdx.x, l = blockIdx.y;
    const int tid = threadIdx.x, nl = tid & 63, ks = tid >> 6, n = x * 64 + nl;
    const float *pa, *pb; int r;
    if (l < 9)       { pa = h11; pb = h12; r = l; }
    else if (l < 43) { pa = h21; pb = h22; r = l - 9; }
    else             { pa = h31; pb = h32; r = l - 43; }
    for (int j = tid; j < 768; j += 256) {
        float v;
        if (j < 256)      v = pa[r * 256 + j];
        else if (j < 512) v = pb[r * 256 + (j - 256)];
        else              v = tmpP[l * 256 + (j - 512)];
        ls[j] = v;
    }
    __syncthreads();
    float a0 = 0, a1 = 0, a2 = 0, a3 = 0;
    for (int k = ks; k + 12 < 768; k += 16) {
        long o = (long)k * 256 + n;
        a0 += ls[k] * mix_W[o];        a1 += ls[k + 4] * mix_W[o + 1024];
        a2 += ls[k + 8] * mix_W[o + 2048]; a3 += ls[k + 12] * mix_W[o + 3072];
    }
    red[tid] = a0 + a1 + a2 + a3;
    __syncthreads();
    if (ks == 0) {
        float tot = red[nl] + red[64 + nl] + red[128 + nl] + red[192 + nl] + mix_b[n];
        le_h[(long)l * 256 + n] = f2h(tot);
    }
}

// ---------------------------------------------------------------------------
// att_fused: logits + pad-mask + softmax + PV in one kernel (round-10,
// verified). Unchanged.
// ---------------------------------------------------------------------------
__global__ __launch_bounds__(512, 1) void att_fused(
    const unsigned short* __restrict__ le_h,    // [141][256] f16
    const unsigned short* __restrict__ text_h,  // [64*512][256] f16
    const unsigned short* __restrict__ text_hT, // [64][256][512] f16
    const int* __restrict__ tokens,             // [64][512]
    unsigned short* __restrict__ feat_h)        // [64][141*256] f16
{
    __shared__ unsigned short smem[57344];      // 114688 B
    __shared__ float redm[8][32];
    __shared__ float reds[8][32];
    unsigned short* A_s = smem;                 // logits: [64*256]  (32 KB)
    unsigned short* BsL = smem + 16384;         // logits: 2 x [512*32] (64 KB)
    unsigned short* P   = smem;                 // pv: [64][512] swizzled (64 KB)
    unsigned short* Vb  = smem + 32768;         // pv: 3 x [256*32] (48 KB)

    const int tid  = threadIdx.x;
    const int wave = tid >> 6, lane = tid & 63;
    const int quad = lane >> 4, l16 = lane & 15;
    const int m0 = blockIdx.x * 64;
    const int b  = blockIdx.y;
    const int wm = (wave >> 2) * 32;            // 2 m-groups
    const int wn = (wave & 3) * 128;            // logits: 4 n-groups x 128

    // ==================== Phase 1: logits + mask + softmax ================
    const int bsc = (lane & 3) ^ ((lane >> 3) & 3);
    const long bOffBase = (long)(b * 512 + wave * 64 + (lane >> 2)) * 256 + bsc * 8;
    const int bDstBase = (wave * 64) * 32;
    auto issueB = [&](int kt, int pb) {
        #pragma unroll
        for (int q = 0; q < 4; q++)
            gload_lds16(text_h + bOffBase + (long)q * 16 * 256 + kt * 32,
                        &BsL[pb * 16384 + bDstBase + q * 16 * 32]);
    };

    int abase[2], axm[2], bro[8];
    #pragma unroll
    for (int i = 0; i < 2; i++) {
        int r = wm + i * 16 + l16;
        abase[i] = r * 256; axm[i] = r & 7;
    }
    #pragma unroll
    for (int j = 0; j < 8; j++) {
        int n = wn + j * 16 + l16;
        bro[j] = n * 32 + ((quad ^ ((n >> 1) & 3)) << 3);
    }

    #pragma unroll
    for (int p = 0; p < 4; p++) {
        int row = p * 16 + (tid >> 5);
        int c   = tid & 31;
        int grow = m0 + row; if (grow > L - 1) grow = L - 1;
        gload_lds16(le_h + (long)grow * 256 + ((c ^ (row & 7)) << 3),
                    A_s + p * 4096 + wave * 512);
    }
    issueB(0, 0);
    issueB(1, 1);
    asm volatile("s_waitcnt vmcnt(4)" ::: "memory");   // A(4)+B0(4) landed
    asm volatile("s_barrier" ::: "memory");

    f32x4 acc[2][8] = {};
    #pragma unroll 1
    for (int t = 0; t < 8; t++) {
        const int pb = t & 1;
        f16x8 a[2], bf[8];
        #pragma unroll
        for (int i = 0; i < 2; i++)
            a[i] = *(const f16x8*)&A_s[abase[i] + (((t * 4 + quad) ^ axm[i]) << 3)];
        const unsigned short* bb = &BsL[pb * 16384];
        #pragma unroll
        for (int j = 0; j < 8; j++) bf[j] = *(const f16x8*)&bb[bro[j]];
        #pragma unroll
        for (int i = 0; i < 2; i++)
            #pragma unroll
            for (int j = 0; j < 8; j++)
                acc[i][j] = __builtin_amdgcn_mfma_f32_16x16x32_f16(
                    a[i], bf[j], acc[i][j], 0, 0, 0);
        if (t < 7) {
            asm volatile("s_waitcnt lgkmcnt(0)" ::: "memory");
            asm volatile("s_barrier" ::: "memory");
            int kt2 = (t + 2 <= 7) ? t + 2 : 7;
            issueB(kt2, pb);
            asm volatile("s_waitcnt vmcnt(4)" ::: "memory");
            asm volatile("s_barrier" ::: "memory");
        }
    }
    asm volatile("s_waitcnt vmcnt(0)" ::: "memory");   // drain dup DMA (mine)

    float mvv[8];
    #pragma unroll
    for (int j = 0; j < 8; j++) {
        int gs = wn + j * 16 + l16;
        int tok = tokens[(long)b * 512 + gs];
        mvv[j] = (tok == 0 || tok == 101 || tok == 102) ? 1e30f : 0.f;
    }
    #pragma unroll
    for (int i = 0; i < 2; i++)
        #pragma unroll
        for (int j = 0; j < 8; j++)
            #pragma unroll
            for (int r = 0; r < 4; r++) acc[i][j][r] -= mvv[j];

    const int wgrp = (wave >> 2) * 4;
    float M[2][4];
    #pragma unroll
    for (int i = 0; i < 2; i++)
        #pragma unroll
        for (int r = 0; r < 4; r++) {
            float v = acc[i][0][r];
            #pragma unroll
            for (int j = 1; j < 8; j++) v = fmaxf(v, acc[i][j][r]);
            #pragma unroll
            for (int d = 1; d <= 8; d <<= 1) v = fmaxf(v, __shfl_xor(v, d));
            if (l16 == 0) redm[wave][i * 16 + quad * 4 + r] = v;
        }
    __syncthreads();      // all waves past vmcnt(0) drain here -> LDS reusable
    #pragma unroll
    for (int i = 0; i < 2; i++)
        #pragma unroll
        for (int r = 0; r < 4; r++) {
            int rl = i * 16 + quad * 4 + r;
            float v = redm[wgrp][rl];
            #pragma unroll
            for (int k = 1; k < 4; k++) v = fmaxf(v, redm[wgrp + k][rl]);
            M[i][r] = v;
        }

    float psum[2][4] = {};
    #pragma unroll
    for (int i = 0; i < 2; i++)
        #pragma unroll
        for (int j = 0; j < 8; j++)
            #pragma unroll
            for (int r = 0; r < 4; r++) {
                float e = __expf(acc[i][j][r] - M[i][r]);
                acc[i][j][r] = e;
                psum[i][r] += e;
            }
    #pragma unroll
    for (int i = 0; i < 2; i++)
        #pragma unroll
        for (int r = 0; r < 4; r++) {
            float v = psum[i][r];
            #pragma unroll
            for (int d = 1; d <= 8; d <<= 1) v += __shfl_xor(v, d);
            if (l16 == 0) reds[wave][i * 16 + quad * 4 + r] = v;
        }
    __syncthreads();
    #pragma unroll
    for (int i = 0; i < 2; i++)
        #pragma unroll
        for (int r = 0; r < 4; r++) {
            int rl = i * 16 + quad * 4 + r;
            float s = reds[wgrp][rl] + reds[wgrp + 1][rl]
                    + reds[wgrp + 2][rl] + reds[wgrp + 3][rl];
            M[i][r] = 1.f / s;
        }

    // ---- write P to LDS (16B-chunk swizzle c ^= row&7); rows >= L zeroed ----
    #pragma unroll
    for (int i = 0; i < 2; i++)
        #pragma unroll
        for (int r = 0; r < 4; r++) {
            int ml = wm + i * 16 + quad * 4 + r;     // local row 0..63
            int gm = m0 + ml;
            #pragma unroll
            for (int j = 0; j < 8; j++) {
                int col = wn + j * 16 + l16;
                float pv = (gm < L) ? acc[i][j][r] * M[i][r] : 0.f;
                int c = col >> 3, w = col & 7;
                P[ml * 512 + ((c ^ (ml & 7)) << 3) + w] = f2h(pv);
            }
        }

    // ==================== Phase 2: PV (att_pv minus A-staging) ============
    const int wnp = (wave & 3) * 64;
    const long vOff0 = ((long)b * 256 + wave * 32 + (lane >> 2)) * 512 + bsc * 8;
    const long vOff1 = vOff0 + 16 * 512;
    const int vDst0 = (wave * 32) * 32, vDst1 = vDst0 + 16 * 32;
    auto issueV = [&](int kt, int pb) {
        gload_lds16(text_hT + vOff0 + kt * 32, Vb + pb * 8192 + vDst0);
        gload_lds16(text_hT + vOff1 + kt * 32, Vb + pb * 8192 + vDst1);
    };
    int paro[2], pxm[2], vro[4];
    #pragma unroll
    for (int i = 0; i < 2; i++) {
        int r = wm + i * 16 + l16;
        paro[i] = r * 512; pxm[i] = r & 7;
    }
    #pragma unroll
    for (int j = 0; j < 4; j++) {
        int n = wnp + j * 16 + l16;
        vro[j] = n * 32 + ((quad ^ ((n >> 1) & 3)) << 3);
    }

    issueV(0, 0);
    issueV(1, 1);
    asm volatile("s_waitcnt lgkmcnt(0)" ::: "memory");  // my P writes done
    asm volatile("s_waitcnt vmcnt(2)" ::: "memory");    // V(0) landed (own)
    asm volatile("s_barrier" ::: "memory");             // all P visible

    f32x4 accp[2][4] = {};
    #pragma unroll 1
    for (int t = 0; t < 16; t++) {
        const int pr = t % 3;
        f16x8 a2[2], vf[4];
        #pragma unroll
        for (int i = 0; i < 2; i++)
            a2[i] = *(const f16x8*)&P[paro[i] + (((t * 4 + quad) ^ pxm[i]) << 3)];
        const unsigned short* vb = Vb + pr * 8192;
        #pragma unroll
        for (int j = 0; j < 4; j++) vf[j] = *(const f16x8*)&vb[vro[j]];
        #pragma unroll
        for (int i = 0; i < 2; i++)
            #pragma unroll
            for (int j = 0; j < 4; j++)
                accp[i][j] = __builtin_amdgcn_mfma_f32_16x16x32_f16(
                    a2[i], vf[j], accp[i][j], 0, 0, 0);
        if (t < 15) {
            int kb = t + 2; if (kb > 15) kb = 15;       // tail: dup, dead buf
            issueV(kb, (t + 2) % 3);
            asm volatile("s_waitcnt vmcnt(2)" ::: "memory");
            asm volatile("s_barrier" ::: "memory");
        }
    }
    asm volatile("s_waitcnt vmcnt(0)" ::: "memory");

    // ---- epilogue: f16 store ----
    #pragma unroll
    for (int i = 0; i < 2; i++)
        #pragma unroll
        for (int j = 0; j < 4; j++)
            #pragma unroll
            for (int r = 0; r < 4; r++) {
                int gm = m0 + wm + i * 16 + quad * 4 + r;
                if (gm < L) {
                    int h = wnp + j * 16 + l16;
                    feat_h[(long)b * (L * H) + (long)gm * 256 + h] =
                        f2h(accp[i][j][r]);
                }
            }
}

// ---------------------------------------------------------------------------
// MFMA fp16 GEMM (EPI4 only). Tile = (32*IM) x 128, BK=32, 4 waves.
// ---------------------------------------------------------------------------
template<int EPI, bool CONVA, int IM>
__global__ __launch_bounds__(256) void gemm_mfma(
    const void* __restrict__ Aptr, int lda, long strA,
    const unsigned short* __restrict__ Bp, int ldb, long strB,
    float* __restrict__ C, int ldc, long strC,
    int M, int N, int K,
    const float* __restrict__ bias,
    const int* __restrict__ tokens,
    unsigned short* __restrict__ outH,
    unsigned short* __restrict__ outHT,
    int kChunk)
{
    __shared__ unsigned short A_s[32 * IM * 32];
    __shared__ unsigned short B_s[128 * 32];
    const int tid  = threadIdx.x;
    const int wave = tid >> 6, lane = tid & 63;
    const int quad = lane >> 4, l16 = lane & 15;
    const int bz = blockIdx.z;
    const int m0 = blockIdx.y * (32 * IM), n0 = blockIdx.x * 128;
    const int wm = (wave & 1) * (16 * IM), wn = (wave >> 1) * 64;

    long aBase, bBase;
    int kBeg, kEnd;
    if (EPI == 4) { aBase = 0; bBase = 0; kBeg = bz * kChunk; kEnd = kBeg + kChunk; }
    else { aBase = (long)bz * strA; bBase = (long)bz * strB; kBeg = 0; kEnd = K; }

    f32x4 acc[IM][4] = {};

    for (int k0 = kBeg; k0 < kEnd; k0 += 32) {
        if (CONVA) {
            const float* Af = (const float*)Aptr + aBase;
            #pragma unroll
            for (int it = 0; it < IM; it++) {
                int idx = it * 256 + tid;
                int row = idx >> 3, col4 = idx & 7;
                int gm = m0 + row; if (gm > M - 1) gm = M - 1;
                float4 v = *(const float4*)(Af + (long)gm * lda + k0 + col4 * 4);
                unsigned int p0 = f2h(v.x) | ((unsigned int)f2h(v.y) << 16);
                unsigned int p1 = f2h(v.z) | ((unsigned int)f2h(v.w) << 16);
                *(uint2*)&A_s[row * 32 + col4 * 4] = make_uint2(p0, p1);
            }
        } else {
            const unsigned short* Ab = (const unsigned short*)Aptr + aBase;
            #pragma unroll
            for (int t = 0; t < IM / 2; t++) {
                int rowb = wave * (8 * IM) + t * 16;
                int gm = m0 + rowb + (lane >> 2); if (gm > M - 1) gm = M - 1;
                gload_lds16(Ab + (long)gm * lda + k0 + (lane & 3) * 8,
                            &A_s[rowb * 32]);
            }
        }
        #pragma unroll
        for (int t = 0; t < 2; t++) {
            int rowb = wave * 32 + t * 16;
            int gn = n0 + rowb + (lane >> 2); if (gn > N - 1) gn = N - 1;
            gload_lds16(Bp + bBase + (long)gn * ldb + k0 + (lane & 3) * 8,
                        &B_s[rowb * 32]);
        }
        __syncthreads();
        f16x8 a[IM], b[4];
        #pragma unroll
        for (int i = 0; i < IM; i++)
            a[i] = *(const f16x8*)&A_s[(wm + i * 16 + l16) * 32 + quad * 8];
        #pragma unroll
        for (int j = 0; j < 4; j++)
            b[j] = *(const f16x8*)&B_s[(wn + j * 16 + l16) * 32 + quad * 8];
        #pragma unroll
        for (int i = 0; i < IM; i++)
            #pragma unroll
            for (int j = 0; j < 4; j++)
                acc[i][j] = __builtin_amdgcn_mfma_f32_16x16x32_f16(
                    a[i], b[j], acc[i][j], 0, 0, 0);
        __syncthreads();
    }

    #pragma unroll
    for (int i = 0; i < IM; i++) {
        #pragma unroll
        for (int j = 0; j < 4; j++) {
            #pragma unroll
            for (int r = 0; r < 4; r++) {
                int ml = wm + i * 16 + quad * 4 + r;
                int nl = wn + j * 16 + l16;
                int gm = m0 + ml, gn = n0 + nl;
                if (gm >= M || gn >= N) continue;
                float v = acc[i][j][r];
                if (EPI == 2) {
                    int tok = tokens[(long)bz * 512 + gn];
                    if (tok == 0 || tok == 101 || tok == 102) v -= 1e30f;
                    C[(long)bz * strC + (long)gm * ldc + gn] = v;
                } else if (EPI == 3) {
                    outH[(long)bz * strC + (long)gm * ldc + gn] = f2h(v);
                } else { // EPI 4: partial K-slice
                    C[(long)bz * strC + (long)gm * ldc + gn] = v;
                }
            }
        }
    }
}

// out = sigmoid(bias + sum of nz partial K-slices)
__global__ __launch_bounds__(256) void out_final(
    const float* __restrict__ acc, const float* __restrict__ ob,
    float* __restrict__ out, int total, int nz)
{
    int i = blockIdx.x * 256 + threadIdx.x;
    if (i >= total) return;
    float v = ob[i % L];
    #pragma unroll 4
    for (int z = 0; z < nz; z++) v += acc[(long)z * total + i];
    out[i] = sigf(v);
}

extern "C" void kernel_launch(void* const* d_in, const int* in_sizes, int n_in,
                              void* d_out, int out_size, void* d_ws, size_t ws_size,
                              hipStream_t stream)
{
    (void)in_sizes; (void)n_in; (void)out_size; (void)ws_size;
    const int*   inputs      = (const int*)d_in[0];
    const float* text_hidden = (const float*)d_in[1];
    const float* label_enc   = (const float*)d_in[2];
    const float* w12   = (const float*)d_in[3];
    const float* w23   = (const float*)d_in[4];
    const float* fre12 = (const float*)d_in[5];
    const float* fre23 = (const float*)d_in[6];
    const float* wi1_W = (const float*)d_in[7],  *wi1_b = (const float*)d_in[8];
    const float* wf1_W = (const float*)d_in[9],  *wf1_b = (const float*)d_in[10];
    const float* wo1_W = (const float*)d_in[11], *wo1_b = (const float*)d_in[12];
    const float* wu1_W = (const float*)d_in[13], *wu1_b = (const float*)d_in[14];
    const float* wi2_W = (const float*)d_in[15], *wi2_b = (const float*)d_in[16];
    const float* wf2_W = (const float*)d_in[17], *wf2_b = (const float*)d_in[18];
    const float* wo2_W = (const float*)d_in[19], *wo2_b = (const float*)d_in[20];
    const float* wu2_W = (const float*)d_in[21], *wu2_b = (const float*)d_in[22];
    const float* ui1_W = (const float*)d_in[23], *uf1_W = (const float*)d_in[24];
    const float* uo1_W = (const float*)d_in[25], *uu1_W = (const float*)d_in[26];
    const float* ui2_W = (const float*)d_in[27], *uf2_W = (const float*)d_in[28];
    const float* uo2_W = (const float*)d_in[29], *uu2_W = (const float*)d_in[30];
    const float* mix_W = (const float*)d_in[31], *mix_b = (const float*)d_in[32];
    const float* tt_W  = (const float*)d_in[33], *tt_b  = (const float*)d_in[34];
    const float* Amat  = (const float*)d_in[35], *Wp    = (const float*)d_in[36];
    const float* out_W = (const float*)d_in[37], *out_b = (const float*)d_in[38];
    float* out = (float*)d_out;

    // ---- workspace (float units, 16B-aligned chunks) ----
    float* ws = (float*)d_ws;
    float* att     = ws; ws += (long)B * L * S;                                 // (unused, layout kept)
    unsigned short* text_h  = (unsigned short*)ws; ws += (long)B * S * H / 2;   // [b*s][h]
    unsigned short* text_hT = (unsigned short*)ws; ws += (long)B * S * H / 2;   // [b][h][s]
    unsigned short* att_h   = (unsigned short*)ws; ws += (long)B * L * S / 2;   // (unused)
    unsigned short* tt_Wt   = (unsigned short*)ws; ws += 768 * H / 2;           // tiled [24][256][32]
    unsigned short* le_h    = (unsigned short*)ws; ws += L * H / 2 + 4;
    unsigned short* out_Wh  = (unsigned short*)ws; ws += (long)L * 36096 / 2;   // [n][k]
    unsigned short* feat_h  = (unsigned short*)ws; ws += (long)B * L * H / 2;   // [b][l*256+h]
    float* outacc = ws; ws += (long)B * L * 141;                                // partial K-slices
    float* G    = ws; ws += 7 * 141 * 256;
    float* tmpP = ws; ws += L * H;
    float* wv2f = ws; ws += N3 * H;
    float* wv1f = ws; ws += N2 * H;
    float* h11  = ws; ws += N1 * H;  float* c11  = ws; ws += N1 * H;
    float* h21  = ws; ws += N2 * H;  float* c21  = ws; ws += N2 * H;
    float* h21t = ws; ws += N2 * H;  float* c21p = ws; ws += N2 * H;
    float* h31  = ws; ws += N3 * H;  float* h31t = ws; ws += N3 * H;
    float* c31p = ws; ws += N3 * H;
    float* h32  = ws; ws += N3 * H;  float* c32  = ws; ws += N3 * H;
    float* h22  = ws; ws += N2 * H;  float* c22  = ws; ws += N2 * H;
    float* h22t = ws; ws += N2 * H;  float* fcb  = ws; ws += N3 * H;
    float* h12  = ws; ws += N1 * H;  float* h12t = ws; ws += N1 * H;
    float* fc2b = ws; ws += N2 * H;
    (void)att; (void)att_h;

    // 1. prep + gates (ew1 folded in) + pre2
    prep_gates<<<24 + 1692 + 3056 + 1092, 256, 0, stream>>>(
        tt_W, tt_Wt, out_W, out_Wh, label_enc,
        wi1_W, wf1_W, wo1_W, wu1_W, wi2_W, wo2_W, wu2_W,
        wi1_b, wf1_b, wo1_b, wu1_b, wi2_b, wo2_b, wu2_b,
        Amat, w23, w12, Wp, wf2_W, G, tmpP, wv2f, wv1f,
        h11, c11, h32, c32);
    // 2. text = tanh(text_hidden @ tt_W + b) -> fp16 both layouts (pipelined)
    text_gemm3<<<512, 512, 0, stream>>>(
        text_hidden, tt_Wt, tt_b, text_h, text_hT);
    // 3-6. label chain
    chain_mm<<<dim3(4, 200), 256, 0, stream>>>(0, w12, w23, fre23, fre12,
        h11, c11, h32, h21, c21, h22, wv2f, wv1f, wf2_b, uf2_W, c32, c22,
        h21t, c21p, h22t, fcb, h31t, c31p, h12t, fc2b);
    lstm_fused<<<dim3(4, 68), 256, 0, stream>>>(0, G,
        h21t, c21p, h22t, fcb, h31t, c31p, h12t, fc2b, w23, w12,
        ui1_W, uf1_W, uo1_W, uu1_W, ui2_W, uo2_W, uu2_W,
        h21, c21, h22, c22, h31, h12);
    chain_mm<<<dim3(4, 239), 256, 0, stream>>>(1, w12, w23, fre23, fre12,
        h11, c11, h32, h21, c21, h22, wv2f, wv1f, wf2_b, uf2_W, c32, c22,
        h21t, c21p, h22t, fcb, h31t, c31p, h12t, fc2b);
    lstm_fused<<<dim3(4, 107), 256, 0, stream>>>(1, G,
        h21t, c21p, h22t, fcb, h31t, c31p, h12t, fc2b, w23, w12,
        ui1_W, uf1_W, uo1_W, uu1_W, ui2_W, uo2_W, uu2_W,
        h21, c21, h22, c22, h31, h12);
    mix_mm<<<dim3(4, 141), 256, 0, stream>>>(h11, h12, h21, h22, h31, h32,
        tmpP, mix_W, mix_b, le_h);
    // 7. logits + mask + softmax + PV fused -> feat_h
    att_fused<<<dim3(3, 64), 512, 0, stream>>>(
        le_h, text_h, text_hT, inputs, feat_h);
    // 8. out-head: K-split MFMA -> 141 partial slices (no atomics)
    gemm_mfma<4, false, 2><<<dim3(2, 1, 141), 256, 0, stream>>>(
        feat_h, L * H, 0, out_Wh, L * H, 0, outacc, L, (long)B * L,
        B, L, L * H, nullptr, nullptr, nullptr, nullptr, 256);
    // 9. reduce + sigmoid + bias
    out_final<<<(B * L + 255) / 256, 256, 0, stream>>>(outacc, out_b, out, B * L, 141);
}